// Round 7
// baseline (370.113 us; speedup 1.0000x reference)
//
#include <hip/hip_runtime.h>
#include <stdint.h>

typedef __attribute__((ext_vector_type(4))) float f32x4;
typedef __attribute__((ext_vector_type(8))) __bf16 bf16x8;
typedef __attribute__((ext_vector_type(8))) unsigned short u16x8;

typedef __attribute__((address_space(1))) const unsigned int guint;
typedef __attribute__((address_space(3))) unsigned int luint;

#if __has_builtin(__builtin_amdgcn_exp2f)
#define EXP2(x) __builtin_amdgcn_exp2f(x)
#else
#define EXP2(x) exp2f(x)
#endif

__device__ __forceinline__ void gload_lds16(const void* g, void* l) {
  __builtin_amdgcn_global_load_lds((guint*)g, (luint*)l, 16, 0, 0);
}

__device__ __forceinline__ unsigned short f2bf(float f) {
  unsigned int u = __builtin_bit_cast(unsigned int, f);
  u += 0x7fffu + ((u >> 16) & 1u);   // RNE
  return (unsigned short)(u >> 16);
}

__device__ __forceinline__ void cvt8(const float* src, unsigned short* dst) {
  float4 a = *(const float4*)(src);
  float4 b = *(const float4*)(src + 4);
  u16x8 r;
  r[0] = f2bf(a.x); r[1] = f2bf(a.y); r[2] = f2bf(a.z); r[3] = f2bf(a.w);
  r[4] = f2bf(b.x); r[5] = f2bf(b.y); r[6] = f2bf(b.z); r[7] = f2bf(b.w);
  *(u16x8*)(dst) = r;
}

// ---------------- single fp32 -> bf16 convert (fallback path) ----------------
__global__ __launch_bounds__(256) void cvt_f32_bf16(const float* __restrict__ in,
                                                    unsigned short* __restrict__ out,
                                                    int n) {
  int i = ((int)blockIdx.x * 256 + (int)threadIdx.x) * 8;
  if (i >= n) return;
  cvt8(in + i, out + i);
}

// ---------------- 3 activations in one launch: 3 x 2048 blocks ----------------
__global__ __launch_bounds__(256) void cvt3_act(const float* __restrict__ a0,
                                                const float* __restrict__ a1,
                                                const float* __restrict__ a2,
                                                unsigned short* __restrict__ o0,
                                                unsigned short* __restrict__ o1,
                                                unsigned short* __restrict__ o2) {
  int b = (int)blockIdx.x >> 11;
  int i = (((int)blockIdx.x & 2047) * 256 + (int)threadIdx.x) * 8;
  const float* src = (b == 0) ? a0 : (b == 1) ? a1 : a2;
  unsigned short* dst = (b == 0) ? o0 : (b == 1) ? o1 : o2;
  cvt8(src + i, dst + i);
}

// ---------------- 4 weights in one launch: 4 x 512 blocks ----------------
__global__ __launch_bounds__(256) void cvt4_w(const float* __restrict__ a0,
                                              const float* __restrict__ a1,
                                              const float* __restrict__ a2,
                                              const float* __restrict__ a3,
                                              unsigned short* __restrict__ o0,
                                              unsigned short* __restrict__ o1,
                                              unsigned short* __restrict__ o2,
                                              unsigned short* __restrict__ o3) {
  int b = (int)blockIdx.x >> 9;
  int i = (((int)blockIdx.x & 511) * 256 + (int)threadIdx.x) * 8;
  const float* src = (b == 0) ? a0 : (b == 1) ? a1 : (b == 2) ? a2 : a3;
  unsigned short* dst = (b == 0) ? o0 : (b == 1) ? o1 : (b == 2) ? o2 : o3;
  cvt8(src + i, dst + i);
}

// ---------------- GEMM: C[M,N] = A[M,K] @ Bw[N,K]^T, 128x128 tile ----------------
template <int OUTF32>
__global__ __launch_bounds__(256) void gemm_bt(const unsigned short* __restrict__ A,
                                               const unsigned short* __restrict__ Bw,
                                               const float* __restrict__ bias,
                                               void* __restrict__ Cout,
                                               int M, int N, int K, float alpha) {
  __shared__ __align__(16) unsigned short As[128 * 32];
  __shared__ __align__(16) unsigned short Bs[128 * 32];
  const int tid = threadIdx.x;
  const int lane = tid & 63;
  const int wave = tid >> 6;
  const int wr = wave >> 1, wc = wave & 1;
  const int ln = lane & 15, lg = lane >> 4;

  const int nwg = (int)gridDim.x;
  int bid = (int)blockIdx.x;
  int swz = (bid & 7) * (nwg >> 3) + (bid >> 3);
  const int nbn = N >> 7;
  const int bm = swz / nbn, bn = swz % nbn;
  const int row0 = bm << 7, col0 = bn << 7;

  f32x4 acc[4][4] = {};

  for (int kt = 0; kt < K; kt += 32) {
    __syncthreads();
#pragma unroll
    for (int c = 0; c < 2; ++c) {
      int idx = c * 256 + tid;
      int r = idx >> 2, cg = idx & 3;
      gload_lds16(A + (row0 + r) * K + kt + cg * 8, &As[idx * 8]);
    }
#pragma unroll
    for (int c = 0; c < 2; ++c) {
      int idx = c * 256 + tid;
      int r = idx >> 2, cg = idx & 3;
      gload_lds16(Bw + (col0 + r) * K + kt + cg * 8, &Bs[idx * 8]);
    }
    __syncthreads();
    bf16x8 a[4], b[4];
#pragma unroll
    for (int mi = 0; mi < 4; ++mi)
      a[mi] = *(const bf16x8*)&As[(wr * 64 + mi * 16 + ln) * 32 + lg * 8];
#pragma unroll
    for (int ni = 0; ni < 4; ++ni)
      b[ni] = *(const bf16x8*)&Bs[(wc * 64 + ni * 16 + ln) * 32 + lg * 8];
#pragma unroll
    for (int mi = 0; mi < 4; ++mi)
#pragma unroll
      for (int ni = 0; ni < 4; ++ni)
        acc[mi][ni] = __builtin_amdgcn_mfma_f32_16x16x32_bf16(a[mi], b[ni], acc[mi][ni], 0, 0, 0);
  }

#pragma unroll
  for (int mi = 0; mi < 4; ++mi)
#pragma unroll
    for (int ni = 0; ni < 4; ++ni) {
      int n = col0 + wc * 64 + ni * 16 + ln;
      float bv = bias[n];
#pragma unroll
      for (int r = 0; r < 4; ++r) {
        int m = row0 + wr * 64 + mi * 16 + lg * 4 + r;
        float v = (acc[mi][ni][r] + bv) * alpha;
        if (OUTF32)
          ((float*)Cout)[(size_t)m * N + n] = v;
        else
          ((unsigned short*)Cout)[(size_t)m * N + n] = f2bf(v);
      }
    }
}

// ------- Batched QKV GEMM: 3 x [4096,1024]x[1024,1024]^T, grid 768, 3 blk/CU -------
__global__ __launch_bounds__(256) void gemm_qkv(
    const unsigned short* __restrict__ Aq, const unsigned short* __restrict__ Ak,
    const unsigned short* __restrict__ Av,
    const unsigned short* __restrict__ Wqb, const unsigned short* __restrict__ Wkb,
    const unsigned short* __restrict__ Wvb,
    const float* __restrict__ bqp, const float* __restrict__ bkp,
    const float* __restrict__ bvp,
    unsigned short* __restrict__ Cq, unsigned short* __restrict__ Ck,
    unsigned short* __restrict__ Cv, float alphaQ) {
  const int K = 1024, N = 1024;
  __shared__ __align__(16) unsigned short As[128 * 32];
  __shared__ __align__(16) unsigned short Bs[128 * 32];
  const int tid = threadIdx.x;
  const int lane = tid & 63;
  const int wave = tid >> 6;
  const int wr = wave >> 1, wc = wave & 1;
  const int ln = lane & 15, lg = lane >> 4;

  int bid = (int)blockIdx.x;
  int swz = (bid & 7) * 96 + (bid >> 3);   // nwg=768
  const int bm = swz >> 3, bn = swz & 7;
  const int batch = bm >> 5, bmL = bm & 31;
  const unsigned short* A;
  const unsigned short* Bw;
  const float* bias;
  unsigned short* C;
  float alpha;
  if (batch == 0)      { A = Aq; Bw = Wqb; bias = bqp; C = Cq; alpha = alphaQ; }
  else if (batch == 1) { A = Ak; Bw = Wkb; bias = bkp; C = Ck; alpha = 1.0f; }
  else                 { A = Av; Bw = Wvb; bias = bvp; C = Cv; alpha = 1.0f; }
  const int row0 = bmL << 7, col0 = bn << 7;

  f32x4 acc[4][4] = {};

  for (int kt = 0; kt < K; kt += 32) {
    __syncthreads();
#pragma unroll
    for (int c = 0; c < 2; ++c) {
      int idx = c * 256 + tid;
      int r = idx >> 2, cg = idx & 3;
      gload_lds16(A + (row0 + r) * K + kt + cg * 8, &As[idx * 8]);
    }
#pragma unroll
    for (int c = 0; c < 2; ++c) {
      int idx = c * 256 + tid;
      int r = idx >> 2, cg = idx & 3;
      gload_lds16(Bw + (col0 + r) * K + kt + cg * 8, &Bs[idx * 8]);
    }
    __syncthreads();
    bf16x8 a[4], b[4];
#pragma unroll
    for (int mi = 0; mi < 4; ++mi)
      a[mi] = *(const bf16x8*)&As[(wr * 64 + mi * 16 + ln) * 32 + lg * 8];
#pragma unroll
    for (int ni = 0; ni < 4; ++ni)
      b[ni] = *(const bf16x8*)&Bs[(wc * 64 + ni * 16 + ln) * 32 + lg * 8];
#pragma unroll
    for (int mi = 0; mi < 4; ++mi)
#pragma unroll
      for (int ni = 0; ni < 4; ++ni)
        acc[mi][ni] = __builtin_amdgcn_mfma_f32_16x16x32_bf16(a[mi], b[ni], acc[mi][ni], 0, 0, 0);
  }

#pragma unroll
  for (int mi = 0; mi < 4; ++mi)
#pragma unroll
    for (int ni = 0; ni < 4; ++ni) {
      int n = col0 + wc * 64 + ni * 16 + ln;
      float bv = bias[n];
#pragma unroll
      for (int r = 0; r < 4; ++r) {
        int m = row0 + wr * 64 + mi * 16 + lg * 4 + r;
        C[(size_t)m * N + n] = f2bf((acc[mi][ni][r] + bv) * alpha);
      }
    }
}

// ------- Out-proj GEMM: 128x64 tile, f32 out, grid 512 (2 blk/CU) -------
__global__ __launch_bounds__(256) void gemm_bt64_f32(const unsigned short* __restrict__ A,
                                                     const unsigned short* __restrict__ Bw,
                                                     const float* __restrict__ bias,
                                                     float* __restrict__ Cout) {
  const int K = 1024, N = 1024;
  __shared__ __align__(16) unsigned short As[128 * 32];
  __shared__ __align__(16) unsigned short Bs[64 * 32];
  const int tid = threadIdx.x;
  const int lane = tid & 63;
  const int wr = tid >> 6;          // wave = 32-row strip
  const int ln = lane & 15, lg = lane >> 4;

  int bid = (int)blockIdx.x;
  int swz = (bid & 7) * 64 + (bid >> 3);   // nwg=512
  const int bm = swz >> 4, bn = swz & 15;
  const int row0 = bm << 7, col0 = bn << 6;

  f32x4 acc[2][4] = {};

  for (int kt = 0; kt < K; kt += 32) {
    __syncthreads();
#pragma unroll
    for (int c = 0; c < 2; ++c) {
      int idx = c * 256 + tid;
      int r = idx >> 2, cg = idx & 3;
      gload_lds16(A + (row0 + r) * K + kt + cg * 8, &As[idx * 8]);
    }
    {
      int r = tid >> 2, cg = tid & 3;
      gload_lds16(Bw + (col0 + r) * K + kt + cg * 8, &Bs[tid * 8]);
    }
    __syncthreads();
    bf16x8 a[2], b[4];
#pragma unroll
    for (int mi = 0; mi < 2; ++mi)
      a[mi] = *(const bf16x8*)&As[(wr * 32 + mi * 16 + ln) * 32 + lg * 8];
#pragma unroll
    for (int ni = 0; ni < 4; ++ni)
      b[ni] = *(const bf16x8*)&Bs[(ni * 16 + ln) * 32 + lg * 8];
#pragma unroll
    for (int mi = 0; mi < 2; ++mi)
#pragma unroll
      for (int ni = 0; ni < 4; ++ni)
        acc[mi][ni] = __builtin_amdgcn_mfma_f32_16x16x32_bf16(a[mi], b[ni], acc[mi][ni], 0, 0, 0);
  }

#pragma unroll
  for (int mi = 0; mi < 2; ++mi)
#pragma unroll
    for (int ni = 0; ni < 4; ++ni) {
      int n = col0 + ni * 16 + ln;
      float bv = bias[n];
#pragma unroll
      for (int r = 0; r < 4; ++r) {
        int m = row0 + wr * 32 + mi * 16 + lg * 4 + r;
        Cout[(size_t)m * N + n] = acc[mi][ni][r] + bv;
      }
    }
}

// ---------------- V transpose per head: [32][2048][64] -> [32][64][2048] ----
// Output keys PERMUTED within each 64-key tile to match the P-store layout:
//   storage pos(k) = (k>>5)*32 + (k&15)*2 + ((k>>4)&1)
__global__ __launch_bounds__(256) void transpose_v(const unsigned short* __restrict__ V,
                                                   unsigned short* __restrict__ Vt) {
  __shared__ unsigned short t[64][65];
  const int g = (int)blockIdx.x >> 5;
  const int kt = (int)blockIdx.x & 31;
  const int tid = threadIdx.x;
  const int base = g << 17;
#pragma unroll
  for (int h = 0; h < 2; ++h) {
    int key = (tid >> 3) + h * 32, d0 = (tid & 7) * 8;
    u16x8 v = *(const u16x8*)(V + base + (kt * 64 + key) * 64 + d0);
#pragma unroll
    for (int j = 0; j < 8; ++j) t[d0 + j][key] = v[j];
  }
  __syncthreads();
  {
    int d = tid >> 2, q3 = tid & 3;
    u16x8 r0, r1;
#pragma unroll
    for (int i = 0; i < 8; ++i) {
      int k = (q3 >> 1) * 32 + (i & 1) * 16 + (q3 & 1) * 8 + (i >> 1);
      r0[i] = t[d][k];
    }
#pragma unroll
    for (int i = 8; i < 16; ++i) {
      int k = (q3 >> 1) * 32 + (i & 1) * 16 + (q3 & 1) * 8 + (i >> 1);
      r1[i - 8] = t[d][k];
    }
    unsigned short* o = Vt + base + d * 2048 + kt * 64 + q3 * 16;
    *(u16x8*)(o) = r0;
    *(u16x8*)(o + 8) = r1;
  }
}

// ---------------- Flash attention over 32 heads of [2048,64] ----------------
// Q pre-scaled by (1/8)*log2(e): p = exp2(S), no max tracking.
// R7: NSPLIT=2 KV-split (16 tiles/block, f32 unnormalized partials + l) for
// 16 waves/CU; bank-conflict fix: P XOR key = (row&7)<<2 (16B granularity,
// 2-way = free on both write and read; R6's (ln>>2) key was 4-way on read).
template <int NSPLIT>
__global__ __launch_bounds__(128, 4) void attn_kernel(const unsigned short* __restrict__ Q,
                                                      const unsigned short* __restrict__ Km,
                                                      const unsigned short* __restrict__ Vt,
                                                      unsigned short* __restrict__ O,
                                                      float* __restrict__ pO,
                                                      float* __restrict__ pl) {
  __shared__ __align__(16) unsigned short Ps[2][2][32 * 64];  // [wave][parity]
  const int tid = threadIdx.x;
  const int lane = tid & 63, wave = tid >> 6;
  const int ln = lane & 15, lg = lane >> 4;

  const int bid = (int)blockIdx.x;
  const int sp = (NSPLIT == 2) ? (bid >> 10) : 0;
  const int low = bid & 1023;
  const int g = (low & 7) + ((low >> 8) << 3);
  const int qt = (low >> 3) & 31;
  const int base = g << 17;
  const int qrow0 = qt * 64 + wave * 32;
  const int kv0 = sp * (32 / NSPLIT);
  const int NT = 32 / NSPLIT;

  bf16x8 aq[2][2];
#pragma unroll
  for (int mb = 0; mb < 2; ++mb)
#pragma unroll
    for (int kb = 0; kb < 2; ++kb)
      aq[mb][kb] = *(const bf16x8*)(Q + base + (qrow0 + mb * 16 + ln) * 64 + kb * 32 + lg * 8);

  float l_p[2][4] = {};
  f32x4 acc_o[2][4] = {};
  f32x4 s[2][4];
  bf16x8 Kf[2][4], Vf[2][4], ap[2][2];

  auto loadK = [&](int kv) {
    const unsigned short* Kt = Km + base + (kv << 12);
#pragma unroll
    for (int kb = 0; kb < 2; ++kb)
#pragma unroll
      for (int nb = 0; nb < 4; ++nb)
        Kf[kb][nb] = *(const bf16x8*)(Kt + (nb * 16 + ln) * 64 + kb * 32 + lg * 8);
  };
  auto loadV = [&](int kv) {
    const unsigned short* Vp = Vt + base + kv * 64;
#pragma unroll
    for (int kb = 0; kb < 2; ++kb)
#pragma unroll
      for (int nd = 0; nd < 4; ++nd)
        Vf[kb][nd] = *(const bf16x8*)(Vp + (nd * 16 + ln) * 2048 + kb * 32 + lg * 8);
  };
  auto QK = [&]() {
#pragma unroll
    for (int mb = 0; mb < 2; ++mb)
#pragma unroll
      for (int nb = 0; nb < 4; ++nb)
        s[mb][nb] = (f32x4){0.f, 0.f, 0.f, 0.f};
    __builtin_amdgcn_s_setprio(1);
#pragma unroll
    for (int kb = 0; kb < 2; ++kb)
#pragma unroll
      for (int nb = 0; nb < 4; ++nb)
#pragma unroll
        for (int mb = 0; mb < 2; ++mb)
          s[mb][nb] = __builtin_amdgcn_mfma_f32_16x16x32_bf16(aq[mb][kb], Kf[kb][nb], s[mb][nb], 0, 0, 0);
    __builtin_amdgcn_s_setprio(0);
  };
  auto PVload = [&](int parR) {
    const unsigned short* PR = &Ps[wave][parR][0];
#pragma unroll
    for (int kb = 0; kb < 2; ++kb)
#pragma unroll
      for (int mb = 0; mb < 2; ++mb) {
        int row = mb * 16 + ln;
        ap[kb][mb] = *(const bf16x8*)&PR[row * 64 +
                                        (((kb * 16 + lg * 4) ^ ((row & 7) << 2)) << 1)];
      }
  };
  auto SM = [&](int parW) {
    unsigned int* PW = (unsigned int*)&Ps[wave][parW][0];
#pragma unroll
    for (int mb = 0; mb < 2; ++mb)
#pragma unroll
      for (int r = 0; r < 4; ++r) {
        int q = mb * 16 + lg * 4 + r;
        float p0 = EXP2(s[mb][0][r]);
        float p1 = EXP2(s[mb][1][r]);
        float p2 = EXP2(s[mb][2][r]);
        float p3 = EXP2(s[mb][3][r]);
        unsigned int d0, d1;
        asm("v_cvt_pk_bf16_f32 %0, %1, %2" : "=v"(d0) : "v"(p0), "v"(p1));
        asm("v_cvt_pk_bf16_f32 %0, %1, %2" : "=v"(d1) : "v"(p2), "v"(p3));
        int dwb = q * 32;
        int x = (q & 7) << 2;
        PW[dwb + (ln ^ x)] = d0;            // keys (ln, ln+16)
        PW[dwb + ((16 + ln) ^ x)] = d1;     // keys (32+ln, 48+ln)
        l_p[mb][r] += (p0 + p1) + (p2 + p3);
      }
  };
  auto PVmma = [&]() {
    __builtin_amdgcn_s_setprio(1);
#pragma unroll
    for (int kb = 0; kb < 2; ++kb)
#pragma unroll
      for (int nd = 0; nd < 4; ++nd)
#pragma unroll
        for (int mb = 0; mb < 2; ++mb)
          acc_o[mb][nd] = __builtin_amdgcn_mfma_f32_16x16x32_bf16(ap[kb][mb], Vf[kb][nd], acc_o[mb][nd], 0, 0, 0);
    __builtin_amdgcn_s_setprio(0);
  };

  // prologue: tile kv0
  loadK(kv0); loadV(kv0);
  QK();
  loadK(kv0 + 1);
  SM(0);
  // steady state
  for (int i = 1; i < NT; ++i) {
    QK();
    loadK(kv0 + (i + 1 < NT ? i + 1 : NT - 1));
    PVload((i - 1) & 1);
    SM(i & 1);
    PVmma();
    loadV(kv0 + i);
  }
  PVload((NT - 1) & 1);
  PVmma();

  if (NSPLIT == 1) {
#pragma unroll
    for (int mb = 0; mb < 2; ++mb)
#pragma unroll
      for (int r = 0; r < 4; ++r) {
        float ls = l_p[mb][r];
        ls += __shfl_xor(ls, 1);
        ls += __shfl_xor(ls, 2);
        ls += __shfl_xor(ls, 4);
        ls += __shfl_xor(ls, 8);
        float inv = 1.f / ls;
        int row = qrow0 + mb * 16 + lg * 4 + r;
#pragma unroll
        for (int nd = 0; nd < 4; ++nd)
          O[base + row * 64 + nd * 16 + ln] = f2bf(acc_o[mb][nd][r] * inv);
      }
  } else {
    // unnormalized partials: acc f32 + l f32
    float* pOb = pO + (size_t)(sp * 32 + g) * (2048 * 64);
#pragma unroll
    for (int mb = 0; mb < 2; ++mb)
#pragma unroll
      for (int r = 0; r < 4; ++r) {
        float ls = l_p[mb][r];
        ls += __shfl_xor(ls, 1);
        ls += __shfl_xor(ls, 2);
        ls += __shfl_xor(ls, 4);
        ls += __shfl_xor(ls, 8);
        int row = qrow0 + mb * 16 + lg * 4 + r;
#pragma unroll
        for (int nd = 0; nd < 4; ++nd)
          pOb[row * 64 + nd * 16 + ln] = acc_o[mb][nd][r];
        if (ln == 0) pl[(sp * 32 + g) * 2048 + row] = ls;
      }
  }
}

// ---------------- combine: O = (acc0+acc1)/(l0+l1), bf16 out ----------------
__global__ __launch_bounds__(256) void attn_combine(const float* __restrict__ pO,
                                                    const float* __restrict__ pl,
                                                    unsigned short* __restrict__ O) {
  const int SPO = 32 * 2048 * 64;   // 4194304
  int idx = ((int)blockIdx.x * 256 + (int)threadIdx.x) * 8;
  int row = idx >> 6;
  float inv = 1.f / (pl[row] + pl[65536 + row]);
  float4 a0 = *(const float4*)(pO + idx);
  float4 a1 = *(const float4*)(pO + idx + 4);
  float4 b0 = *(const float4*)(pO + SPO + idx);
  float4 b1 = *(const float4*)(pO + SPO + idx + 4);
  u16x8 r;
  r[0] = f2bf((a0.x + b0.x) * inv); r[1] = f2bf((a0.y + b0.y) * inv);
  r[2] = f2bf((a0.z + b0.z) * inv); r[3] = f2bf((a0.w + b0.w) * inv);
  r[4] = f2bf((a1.x + b1.x) * inv); r[5] = f2bf((a1.y + b1.y) * inv);
  r[6] = f2bf((a1.z + b1.z) * inv); r[7] = f2bf((a1.w + b1.w) * inv);
  *(u16x8*)(O + idx) = r;
}

// ---------------- launch ----------------
extern "C" void kernel_launch(void* const* d_in, const int* in_sizes, int n_in,
                              void* d_out, int out_size, void* d_ws, size_t ws_size,
                              hipStream_t stream) {
  const float* query = (const float*)d_in[0];
  const float* key   = (const float*)d_in[1];
  const float* value = (const float*)d_in[2];
  const float* Wq = (const float*)d_in[3];
  const float* bq = (const float*)d_in[4];
  const float* Wk = (const float*)d_in[5];
  const float* bk = (const float*)d_in[6];
  const float* Wv = (const float*)d_in[7];
  const float* bv = (const float*)d_in[8];
  const float* Wo = (const float*)d_in[9];
  const float* bo = (const float*)d_in[10];

  const int ACT = 4096 * 1024;
  const int WEL = 1024 * 1024;
  const int M = 4096, N = 1024, Kd = 1024;
  const float ALPHA_Q = 0.125f * 1.44269504f;   // 1/sqrt(64) * log2(e)

  char* ws = (char*)d_ws;
  dim3 blk(256);

  if (ws_size >= (size_t)(56u * 1024u * 1024u)) {
    // ---- Path A: batched QKV + (if room) split-KV attention ----
    unsigned short* Xq  = (unsigned short*)(ws);
    unsigned short* Vtb = (unsigned short*)(ws);
    unsigned short* Xk  = (unsigned short*)(ws + (8u << 20));
    unsigned short* Ob  = (unsigned short*)(ws + (8u << 20));
    unsigned short* Xv  = (unsigned short*)(ws + (16u << 20));
    unsigned short* Wqb = (unsigned short*)(ws + (24u << 20));
    unsigned short* Wkb = (unsigned short*)(ws + (26u << 20));
    unsigned short* Wvb = (unsigned short*)(ws + (28u << 20));
    unsigned short* Wob = (unsigned short*)(ws + (30u << 20));
    unsigned short* Qb  = (unsigned short*)(ws + (32u << 20));
    unsigned short* Kb  = (unsigned short*)(ws + (40u << 20));
    unsigned short* Vb  = (unsigned short*)(ws + (48u << 20));
    float* pO = (float*)(ws + (56u << 20));       // 32 MB (2 splits x 16 MB)
    float* pl = (float*)(ws + (88u << 20));       // 512 KB

    cvt3_act<<<dim3(3 * 2048), blk, 0, stream>>>(query, key, value, Xq, Xk, Xv);
    cvt4_w<<<dim3(4 * 512), blk, 0, stream>>>(Wq, Wk, Wv, Wo, Wqb, Wkb, Wvb, Wob);
    gemm_qkv<<<dim3(768), blk, 0, stream>>>(Xq, Xk, Xv, Wqb, Wkb, Wvb,
                                            bq, bk, bv, Qb, Kb, Vb, ALPHA_Q);
    transpose_v<<<dim3(1024), blk, 0, stream>>>(Vb, Vtb);
    if (ws_size >= (size_t)(89u * 1024u * 1024u)) {
      attn_kernel<2><<<dim3(2048), dim3(128), 0, stream>>>(Qb, Kb, Vtb, Ob, pO, pl);
      attn_combine<<<dim3(2048), blk, 0, stream>>>(pO, pl, Ob);
    } else {
      attn_kernel<1><<<dim3(1024), dim3(128), 0, stream>>>(Qb, Kb, Vtb, Ob, pO, pl);
    }
    gemm_bt64_f32<<<dim3(512), blk, 0, stream>>>(Ob, Wob, bo, (float*)d_out);
  } else {
    // ---- Path B: sequential (34 MB workspace) ----
    unsigned short* X   = (unsigned short*)(ws);
    unsigned short* Vtb = (unsigned short*)(ws);
    unsigned short* W   = (unsigned short*)(ws + 8388608);
    unsigned short* Qb  = (unsigned short*)(ws + 10485760);
    unsigned short* Kb  = (unsigned short*)(ws + 18874368);
    unsigned short* Vb  = (unsigned short*)(ws + 27262976);
    unsigned short* Ob  = (unsigned short*)(ws + 27262976);

    cvt_f32_bf16<<<dim3(ACT / 2048), blk, 0, stream>>>(query, X, ACT);
    cvt_f32_bf16<<<dim3(WEL / 2048), blk, 0, stream>>>(Wq, W, WEL);
    gemm_bt<0><<<dim3(256), blk, 0, stream>>>(X, W, bq, (void*)Qb, M, N, Kd, ALPHA_Q);

    cvt_f32_bf16<<<dim3(ACT / 2048), blk, 0, stream>>>(key, X, ACT);
    cvt_f32_bf16<<<dim3(WEL / 2048), blk, 0, stream>>>(Wk, W, WEL);
    gemm_bt<0><<<dim3(256), blk, 0, stream>>>(X, W, bk, (void*)Kb, M, N, Kd, 1.0f);

    cvt_f32_bf16<<<dim3(ACT / 2048), blk, 0, stream>>>(value, X, ACT);
    cvt_f32_bf16<<<dim3(WEL / 2048), blk, 0, stream>>>(Wv, W, WEL);
    gemm_bt<0><<<dim3(256), blk, 0, stream>>>(X, W, bv, (void*)Vb, M, N, Kd, 1.0f);

    transpose_v<<<dim3(1024), blk, 0, stream>>>(Vb, Vtb);
    cvt_f32_bf16<<<dim3(WEL / 2048), blk, 0, stream>>>(Wo, W, WEL);
    attn_kernel<1><<<dim3(1024), dim3(128), 0, stream>>>(Qb, Kb, Vtb, Ob, (float*)ws, (float*)ws);
    gemm_bt64_f32<<<dim3(512), blk, 0, stream>>>(Ob, W, bo, (float*)d_out);
  }
}

// Round 8
// 218.759 us; speedup vs baseline: 1.6919x; 1.6919x over previous
//
#include <hip/hip_runtime.h>
#include <stdint.h>

typedef __attribute__((ext_vector_type(4))) float f32x4;
typedef __attribute__((ext_vector_type(8))) __bf16 bf16x8;
typedef __attribute__((ext_vector_type(8))) unsigned short u16x8;

typedef __attribute__((address_space(1))) const unsigned int guint;
typedef __attribute__((address_space(3))) unsigned int luint;

#if __has_builtin(__builtin_amdgcn_exp2f)
#define EXP2(x) __builtin_amdgcn_exp2f(x)
#else
#define EXP2(x) exp2f(x)
#endif

__device__ __forceinline__ void gload_lds16(const void* g, void* l) {
  __builtin_amdgcn_global_load_lds((guint*)g, (luint*)l, 16, 0, 0);
}

__device__ __forceinline__ unsigned short f2bf(float f) {
  unsigned int u = __builtin_bit_cast(unsigned int, f);
  u += 0x7fffu + ((u >> 16) & 1u);   // RNE
  return (unsigned short)(u >> 16);
}

__device__ __forceinline__ void cvt8(const float* src, unsigned short* dst) {
  float4 a = *(const float4*)(src);
  float4 b = *(const float4*)(src + 4);
  u16x8 r;
  r[0] = f2bf(a.x); r[1] = f2bf(a.y); r[2] = f2bf(a.z); r[3] = f2bf(a.w);
  r[4] = f2bf(b.x); r[5] = f2bf(b.y); r[6] = f2bf(b.z); r[7] = f2bf(b.w);
  *(u16x8*)(dst) = r;
}

// ---------------- single fp32 -> bf16 convert (fallback path) ----------------
__global__ __launch_bounds__(256) void cvt_f32_bf16(const float* __restrict__ in,
                                                    unsigned short* __restrict__ out,
                                                    int n) {
  int i = ((int)blockIdx.x * 256 + (int)threadIdx.x) * 8;
  if (i >= n) return;
  cvt8(in + i, out + i);
}

// ---------------- 3 activations in one launch: 3 x 2048 blocks ----------------
__global__ __launch_bounds__(256) void cvt3_act(const float* __restrict__ a0,
                                                const float* __restrict__ a1,
                                                const float* __restrict__ a2,
                                                unsigned short* __restrict__ o0,
                                                unsigned short* __restrict__ o1,
                                                unsigned short* __restrict__ o2) {
  int b = (int)blockIdx.x >> 11;
  int i = (((int)blockIdx.x & 2047) * 256 + (int)threadIdx.x) * 8;
  const float* src = (b == 0) ? a0 : (b == 1) ? a1 : a2;
  unsigned short* dst = (b == 0) ? o0 : (b == 1) ? o1 : o2;
  cvt8(src + i, dst + i);
}

// ---------------- 4 weights in one launch: 4 x 512 blocks ----------------
__global__ __launch_bounds__(256) void cvt4_w(const float* __restrict__ a0,
                                              const float* __restrict__ a1,
                                              const float* __restrict__ a2,
                                              const float* __restrict__ a3,
                                              unsigned short* __restrict__ o0,
                                              unsigned short* __restrict__ o1,
                                              unsigned short* __restrict__ o2,
                                              unsigned short* __restrict__ o3) {
  int b = (int)blockIdx.x >> 9;
  int i = (((int)blockIdx.x & 511) * 256 + (int)threadIdx.x) * 8;
  const float* src = (b == 0) ? a0 : (b == 1) ? a1 : (b == 2) ? a2 : a3;
  unsigned short* dst = (b == 0) ? o0 : (b == 1) ? o1 : (b == 2) ? o2 : o3;
  cvt8(src + i, dst + i);
}

// ---------------- GEMM: C[M,N] = A[M,K] @ Bw[N,K]^T, 128x128 tile ----------------
template <int OUTF32>
__global__ __launch_bounds__(256) void gemm_bt(const unsigned short* __restrict__ A,
                                               const unsigned short* __restrict__ Bw,
                                               const float* __restrict__ bias,
                                               void* __restrict__ Cout,
                                               int M, int N, int K, float alpha) {
  __shared__ __align__(16) unsigned short As[128 * 32];
  __shared__ __align__(16) unsigned short Bs[128 * 32];
  const int tid = threadIdx.x;
  const int lane = tid & 63;
  const int wave = tid >> 6;
  const int wr = wave >> 1, wc = wave & 1;
  const int ln = lane & 15, lg = lane >> 4;

  const int nwg = (int)gridDim.x;
  int bid = (int)blockIdx.x;
  int swz = (bid & 7) * (nwg >> 3) + (bid >> 3);
  const int nbn = N >> 7;
  const int bm = swz / nbn, bn = swz % nbn;
  const int row0 = bm << 7, col0 = bn << 7;

  f32x4 acc[4][4] = {};

  for (int kt = 0; kt < K; kt += 32) {
    __syncthreads();
#pragma unroll
    for (int c = 0; c < 2; ++c) {
      int idx = c * 256 + tid;
      int r = idx >> 2, cg = idx & 3;
      gload_lds16(A + (row0 + r) * K + kt + cg * 8, &As[idx * 8]);
    }
#pragma unroll
    for (int c = 0; c < 2; ++c) {
      int idx = c * 256 + tid;
      int r = idx >> 2, cg = idx & 3;
      gload_lds16(Bw + (col0 + r) * K + kt + cg * 8, &Bs[idx * 8]);
    }
    __syncthreads();
    bf16x8 a[4], b[4];
#pragma unroll
    for (int mi = 0; mi < 4; ++mi)
      a[mi] = *(const bf16x8*)&As[(wr * 64 + mi * 16 + ln) * 32 + lg * 8];
#pragma unroll
    for (int ni = 0; ni < 4; ++ni)
      b[ni] = *(const bf16x8*)&Bs[(wc * 64 + ni * 16 + ln) * 32 + lg * 8];
#pragma unroll
    for (int mi = 0; mi < 4; ++mi)
#pragma unroll
      for (int ni = 0; ni < 4; ++ni)
        acc[mi][ni] = __builtin_amdgcn_mfma_f32_16x16x32_bf16(a[mi], b[ni], acc[mi][ni], 0, 0, 0);
  }

#pragma unroll
  for (int mi = 0; mi < 4; ++mi)
#pragma unroll
    for (int ni = 0; ni < 4; ++ni) {
      int n = col0 + wc * 64 + ni * 16 + ln;
      float bv = bias[n];
#pragma unroll
      for (int r = 0; r < 4; ++r) {
        int m = row0 + wr * 64 + mi * 16 + lg * 4 + r;
        float v = (acc[mi][ni][r] + bv) * alpha;
        if (OUTF32)
          ((float*)Cout)[(size_t)m * N + n] = v;
        else
          ((unsigned short*)Cout)[(size_t)m * N + n] = f2bf(v);
      }
    }
}

// ------- Batched QKV GEMM: 3 x [4096,1024]x[1024,1024]^T, grid 768, 3 blk/CU -------
__global__ __launch_bounds__(256) void gemm_qkv(
    const unsigned short* __restrict__ Aq, const unsigned short* __restrict__ Ak,
    const unsigned short* __restrict__ Av,
    const unsigned short* __restrict__ Wqb, const unsigned short* __restrict__ Wkb,
    const unsigned short* __restrict__ Wvb,
    const float* __restrict__ bqp, const float* __restrict__ bkp,
    const float* __restrict__ bvp,
    unsigned short* __restrict__ Cq, unsigned short* __restrict__ Ck,
    unsigned short* __restrict__ Cv, float alphaQ) {
  const int K = 1024, N = 1024;
  __shared__ __align__(16) unsigned short As[128 * 32];
  __shared__ __align__(16) unsigned short Bs[128 * 32];
  const int tid = threadIdx.x;
  const int lane = tid & 63;
  const int wave = tid >> 6;
  const int wr = wave >> 1, wc = wave & 1;
  const int ln = lane & 15, lg = lane >> 4;

  int bid = (int)blockIdx.x;
  int swz = (bid & 7) * 96 + (bid >> 3);   // nwg=768
  const int bm = swz >> 3, bn = swz & 7;
  const int batch = bm >> 5, bmL = bm & 31;
  const unsigned short* A;
  const unsigned short* Bw;
  const float* bias;
  unsigned short* C;
  float alpha;
  if (batch == 0)      { A = Aq; Bw = Wqb; bias = bqp; C = Cq; alpha = alphaQ; }
  else if (batch == 1) { A = Ak; Bw = Wkb; bias = bkp; C = Ck; alpha = 1.0f; }
  else                 { A = Av; Bw = Wvb; bias = bvp; C = Cv; alpha = 1.0f; }
  const int row0 = bmL << 7, col0 = bn << 7;

  f32x4 acc[4][4] = {};

  for (int kt = 0; kt < K; kt += 32) {
    __syncthreads();
#pragma unroll
    for (int c = 0; c < 2; ++c) {
      int idx = c * 256 + tid;
      int r = idx >> 2, cg = idx & 3;
      gload_lds16(A + (row0 + r) * K + kt + cg * 8, &As[idx * 8]);
    }
#pragma unroll
    for (int c = 0; c < 2; ++c) {
      int idx = c * 256 + tid;
      int r = idx >> 2, cg = idx & 3;
      gload_lds16(Bw + (col0 + r) * K + kt + cg * 8, &Bs[idx * 8]);
    }
    __syncthreads();
    bf16x8 a[4], b[4];
#pragma unroll
    for (int mi = 0; mi < 4; ++mi)
      a[mi] = *(const bf16x8*)&As[(wr * 64 + mi * 16 + ln) * 32 + lg * 8];
#pragma unroll
    for (int ni = 0; ni < 4; ++ni)
      b[ni] = *(const bf16x8*)&Bs[(wc * 64 + ni * 16 + ln) * 32 + lg * 8];
#pragma unroll
    for (int mi = 0; mi < 4; ++mi)
#pragma unroll
      for (int ni = 0; ni < 4; ++ni)
        acc[mi][ni] = __builtin_amdgcn_mfma_f32_16x16x32_bf16(a[mi], b[ni], acc[mi][ni], 0, 0, 0);
  }

#pragma unroll
  for (int mi = 0; mi < 4; ++mi)
#pragma unroll
    for (int ni = 0; ni < 4; ++ni) {
      int n = col0 + wc * 64 + ni * 16 + ln;
      float bv = bias[n];
#pragma unroll
      for (int r = 0; r < 4; ++r) {
        int m = row0 + wr * 64 + mi * 16 + lg * 4 + r;
        C[(size_t)m * N + n] = f2bf((acc[mi][ni][r] + bv) * alpha);
      }
    }
}

// ------- Out-proj GEMM: 128x64 tile, f32 out, grid 512 (2 blk/CU) -------
__global__ __launch_bounds__(256) void gemm_bt64_f32(const unsigned short* __restrict__ A,
                                                     const unsigned short* __restrict__ Bw,
                                                     const float* __restrict__ bias,
                                                     float* __restrict__ Cout) {
  const int K = 1024, N = 1024;
  __shared__ __align__(16) unsigned short As[128 * 32];
  __shared__ __align__(16) unsigned short Bs[64 * 32];
  const int tid = threadIdx.x;
  const int lane = tid & 63;
  const int wr = tid >> 6;          // wave = 32-row strip
  const int ln = lane & 15, lg = lane >> 4;

  int bid = (int)blockIdx.x;
  int swz = (bid & 7) * 64 + (bid >> 3);   // nwg=512
  const int bm = swz >> 4, bn = swz & 15;
  const int row0 = bm << 7, col0 = bn << 6;

  f32x4 acc[2][4] = {};

  for (int kt = 0; kt < K; kt += 32) {
    __syncthreads();
#pragma unroll
    for (int c = 0; c < 2; ++c) {
      int idx = c * 256 + tid;
      int r = idx >> 2, cg = idx & 3;
      gload_lds16(A + (row0 + r) * K + kt + cg * 8, &As[idx * 8]);
    }
    {
      int r = tid >> 2, cg = tid & 3;
      gload_lds16(Bw + (col0 + r) * K + kt + cg * 8, &Bs[tid * 8]);
    }
    __syncthreads();
    bf16x8 a[2], b[4];
#pragma unroll
    for (int mi = 0; mi < 2; ++mi)
      a[mi] = *(const bf16x8*)&As[(wr * 32 + mi * 16 + ln) * 32 + lg * 8];
#pragma unroll
    for (int ni = 0; ni < 4; ++ni)
      b[ni] = *(const bf16x8*)&Bs[(ni * 16 + ln) * 32 + lg * 8];
#pragma unroll
    for (int mi = 0; mi < 2; ++mi)
#pragma unroll
      for (int ni = 0; ni < 4; ++ni)
        acc[mi][ni] = __builtin_amdgcn_mfma_f32_16x16x32_bf16(a[mi], b[ni], acc[mi][ni], 0, 0, 0);
  }

#pragma unroll
  for (int mi = 0; mi < 2; ++mi)
#pragma unroll
    for (int ni = 0; ni < 4; ++ni) {
      int n = col0 + ni * 16 + ln;
      float bv = bias[n];
#pragma unroll
      for (int r = 0; r < 4; ++r) {
        int m = row0 + wr * 32 + mi * 16 + lg * 4 + r;
        Cout[(size_t)m * N + n] = acc[mi][ni][r] + bv;
      }
    }
}

// ---------------- V transpose per head: [32][2048][64] -> [32][64][2048] ----
// Output keys PERMUTED within each 64-key tile to match the P-store layout:
//   storage pos(k) = (k>>5)*32 + (k&15)*2 + ((k>>4)&1)
__global__ __launch_bounds__(256) void transpose_v(const unsigned short* __restrict__ V,
                                                   unsigned short* __restrict__ Vt) {
  __shared__ unsigned short t[64][65];
  const int g = (int)blockIdx.x >> 5;
  const int kt = (int)blockIdx.x & 31;
  const int tid = threadIdx.x;
  const int base = g << 17;
#pragma unroll
  for (int h = 0; h < 2; ++h) {
    int key = (tid >> 3) + h * 32, d0 = (tid & 7) * 8;
    u16x8 v = *(const u16x8*)(V + base + (kt * 64 + key) * 64 + d0);
#pragma unroll
    for (int j = 0; j < 8; ++j) t[d0 + j][key] = v[j];
  }
  __syncthreads();
  {
    int d = tid >> 2, q3 = tid & 3;
    u16x8 r0, r1;
#pragma unroll
    for (int i = 0; i < 8; ++i) {
      int k = (q3 >> 1) * 32 + (i & 1) * 16 + (q3 & 1) * 8 + (i >> 1);
      r0[i] = t[d][k];
    }
#pragma unroll
    for (int i = 8; i < 16; ++i) {
      int k = (q3 >> 1) * 32 + (i & 1) * 16 + (q3 & 1) * 8 + (i >> 1);
      r1[i - 8] = t[d][k];
    }
    unsigned short* o = Vt + base + d * 2048 + kt * 64 + q3 * 16;
    *(u16x8*)(o) = r0;
    *(u16x8*)(o + 8) = r1;
  }
}

// ---------------- Flash attention over 32 heads of [2048,64] ----------------
// Q pre-scaled by (1/8)*log2(e): p = exp2(S), no max tracking.
// R8: split-KV retained; REMOVED the min-waves launch_bounds clause that
// capped the register file at 64 VGPR and spilled ~1.1GB/dispatch to scratch
// (R7 post-mortem). Plain __launch_bounds__(128) like R6 (VGPR 120, no spill).
template <int NSPLIT>
__global__ __launch_bounds__(128) void attn_kernel(const unsigned short* __restrict__ Q,
                                                   const unsigned short* __restrict__ Km,
                                                   const unsigned short* __restrict__ Vt,
                                                   unsigned short* __restrict__ O,
                                                   float* __restrict__ pO,
                                                   float* __restrict__ pl) {
  __shared__ __align__(16) unsigned short Ps[2][2][32 * 64];  // [wave][parity]
  const int tid = threadIdx.x;
  const int lane = tid & 63, wave = tid >> 6;
  const int ln = lane & 15, lg = lane >> 4;

  const int bid = (int)blockIdx.x;
  const int sp = (NSPLIT == 2) ? (bid >> 10) : 0;
  const int low = bid & 1023;
  const int g = (low & 7) + ((low >> 8) << 3);
  const int qt = (low >> 3) & 31;
  const int base = g << 17;
  const int qrow0 = qt * 64 + wave * 32;
  const int kv0 = sp * (32 / NSPLIT);
  const int NT = 32 / NSPLIT;

  bf16x8 aq[2][2];
#pragma unroll
  for (int mb = 0; mb < 2; ++mb)
#pragma unroll
    for (int kb = 0; kb < 2; ++kb)
      aq[mb][kb] = *(const bf16x8*)(Q + base + (qrow0 + mb * 16 + ln) * 64 + kb * 32 + lg * 8);

  float l_p[2][4] = {};
  f32x4 acc_o[2][4] = {};
  f32x4 s[2][4];
  bf16x8 Kf[2][4], Vf[2][4], ap[2][2];

  auto loadK = [&](int kv) {
    const unsigned short* Kt = Km + base + (kv << 12);
#pragma unroll
    for (int kb = 0; kb < 2; ++kb)
#pragma unroll
      for (int nb = 0; nb < 4; ++nb)
        Kf[kb][nb] = *(const bf16x8*)(Kt + (nb * 16 + ln) * 64 + kb * 32 + lg * 8);
  };
  auto loadV = [&](int kv) {
    const unsigned short* Vp = Vt + base + kv * 64;
#pragma unroll
    for (int kb = 0; kb < 2; ++kb)
#pragma unroll
      for (int nd = 0; nd < 4; ++nd)
        Vf[kb][nd] = *(const bf16x8*)(Vp + (nd * 16 + ln) * 2048 + kb * 32 + lg * 8);
  };
  auto QK = [&]() {
#pragma unroll
    for (int mb = 0; mb < 2; ++mb)
#pragma unroll
      for (int nb = 0; nb < 4; ++nb)
        s[mb][nb] = (f32x4){0.f, 0.f, 0.f, 0.f};
    __builtin_amdgcn_s_setprio(1);
#pragma unroll
    for (int kb = 0; kb < 2; ++kb)
#pragma unroll
      for (int nb = 0; nb < 4; ++nb)
#pragma unroll
        for (int mb = 0; mb < 2; ++mb)
          s[mb][nb] = __builtin_amdgcn_mfma_f32_16x16x32_bf16(aq[mb][kb], Kf[kb][nb], s[mb][nb], 0, 0, 0);
    __builtin_amdgcn_s_setprio(0);
  };
  auto PVload = [&](int parR) {
    const unsigned short* PR = &Ps[wave][parR][0];
#pragma unroll
    for (int kb = 0; kb < 2; ++kb)
#pragma unroll
      for (int mb = 0; mb < 2; ++mb) {
        int row = mb * 16 + ln;
        ap[kb][mb] = *(const bf16x8*)&PR[row * 64 +
                                        (((kb * 16 + lg * 4) ^ ((row & 7) << 2)) << 1)];
      }
  };
  auto SM = [&](int parW) {
    unsigned int* PW = (unsigned int*)&Ps[wave][parW][0];
#pragma unroll
    for (int mb = 0; mb < 2; ++mb)
#pragma unroll
      for (int r = 0; r < 4; ++r) {
        int q = mb * 16 + lg * 4 + r;
        float p0 = EXP2(s[mb][0][r]);
        float p1 = EXP2(s[mb][1][r]);
        float p2 = EXP2(s[mb][2][r]);
        float p3 = EXP2(s[mb][3][r]);
        unsigned int d0, d1;
        asm("v_cvt_pk_bf16_f32 %0, %1, %2" : "=v"(d0) : "v"(p0), "v"(p1));
        asm("v_cvt_pk_bf16_f32 %0, %1, %2" : "=v"(d1) : "v"(p2), "v"(p3));
        int dwb = q * 32;
        int x = (q & 7) << 2;
        PW[dwb + (ln ^ x)] = d0;            // keys (ln, ln+16)
        PW[dwb + ((16 + ln) ^ x)] = d1;     // keys (32+ln, 48+ln)
        l_p[mb][r] += (p0 + p1) + (p2 + p3);
      }
  };
  auto PVmma = [&]() {
    __builtin_amdgcn_s_setprio(1);
#pragma unroll
    for (int kb = 0; kb < 2; ++kb)
#pragma unroll
      for (int nd = 0; nd < 4; ++nd)
#pragma unroll
        for (int mb = 0; mb < 2; ++mb)
          acc_o[mb][nd] = __builtin_amdgcn_mfma_f32_16x16x32_bf16(ap[kb][mb], Vf[kb][nd], acc_o[mb][nd], 0, 0, 0);
    __builtin_amdgcn_s_setprio(0);
  };

  // prologue: tile kv0
  loadK(kv0); loadV(kv0);
  QK();
  loadK(kv0 + 1);
  SM(0);
  // steady state
  for (int i = 1; i < NT; ++i) {
    QK();
    loadK(kv0 + (i + 1 < NT ? i + 1 : NT - 1));
    PVload((i - 1) & 1);
    SM(i & 1);
    PVmma();
    loadV(kv0 + i);
  }
  PVload((NT - 1) & 1);
  PVmma();

  if (NSPLIT == 1) {
#pragma unroll
    for (int mb = 0; mb < 2; ++mb)
#pragma unroll
      for (int r = 0; r < 4; ++r) {
        float ls = l_p[mb][r];
        ls += __shfl_xor(ls, 1);
        ls += __shfl_xor(ls, 2);
        ls += __shfl_xor(ls, 4);
        ls += __shfl_xor(ls, 8);
        float inv = 1.f / ls;
        int row = qrow0 + mb * 16 + lg * 4 + r;
#pragma unroll
        for (int nd = 0; nd < 4; ++nd)
          O[base + row * 64 + nd * 16 + ln] = f2bf(acc_o[mb][nd][r] * inv);
      }
  } else {
    // unnormalized partials: acc f32 + l f32
    float* pOb = pO + (size_t)(sp * 32 + g) * (2048 * 64);
#pragma unroll
    for (int mb = 0; mb < 2; ++mb)
#pragma unroll
      for (int r = 0; r < 4; ++r) {
        float ls = l_p[mb][r];
        ls += __shfl_xor(ls, 1);
        ls += __shfl_xor(ls, 2);
        ls += __shfl_xor(ls, 4);
        ls += __shfl_xor(ls, 8);
        int row = qrow0 + mb * 16 + lg * 4 + r;
#pragma unroll
        for (int nd = 0; nd < 4; ++nd)
          pOb[row * 64 + nd * 16 + ln] = acc_o[mb][nd][r];
        if (ln == 0) pl[(sp * 32 + g) * 2048 + row] = ls;
      }
  }
}

// ---------------- combine: O = (acc0+acc1)/(l0+l1), bf16 out ----------------
__global__ __launch_bounds__(256) void attn_combine(const float* __restrict__ pO,
                                                    const float* __restrict__ pl,
                                                    unsigned short* __restrict__ O) {
  const int SPO = 32 * 2048 * 64;   // 4194304
  int idx = ((int)blockIdx.x * 256 + (int)threadIdx.x) * 8;
  int row = idx >> 6;
  float inv = 1.f / (pl[row] + pl[65536 + row]);
  float4 a0 = *(const float4*)(pO + idx);
  float4 a1 = *(const float4*)(pO + idx + 4);
  float4 b0 = *(const float4*)(pO + SPO + idx);
  float4 b1 = *(const float4*)(pO + SPO + idx + 4);
  u16x8 r;
  r[0] = f2bf((a0.x + b0.x) * inv); r[1] = f2bf((a0.y + b0.y) * inv);
  r[2] = f2bf((a0.z + b0.z) * inv); r[3] = f2bf((a0.w + b0.w) * inv);
  r[4] = f2bf((a1.x + b1.x) * inv); r[5] = f2bf((a1.y + b1.y) * inv);
  r[6] = f2bf((a1.z + b1.z) * inv); r[7] = f2bf((a1.w + b1.w) * inv);
  *(u16x8*)(O + idx) = r;
}

// ---------------- launch ----------------
extern "C" void kernel_launch(void* const* d_in, const int* in_sizes, int n_in,
                              void* d_out, int out_size, void* d_ws, size_t ws_size,
                              hipStream_t stream) {
  const float* query = (const float*)d_in[0];
  const float* key   = (const float*)d_in[1];
  const float* value = (const float*)d_in[2];
  const float* Wq = (const float*)d_in[3];
  const float* bq = (const float*)d_in[4];
  const float* Wk = (const float*)d_in[5];
  const float* bk = (const float*)d_in[6];
  const float* Wv = (const float*)d_in[7];
  const float* bv = (const float*)d_in[8];
  const float* Wo = (const float*)d_in[9];
  const float* bo = (const float*)d_in[10];

  const int ACT = 4096 * 1024;
  const int WEL = 1024 * 1024;
  const int M = 4096, N = 1024, Kd = 1024;
  const float ALPHA_Q = 0.125f * 1.44269504f;   // 1/sqrt(64) * log2(e)

  char* ws = (char*)d_ws;
  dim3 blk(256);

  if (ws_size >= (size_t)(56u * 1024u * 1024u)) {
    // ---- Path A: batched QKV + (if room) split-KV attention ----
    unsigned short* Xq  = (unsigned short*)(ws);
    unsigned short* Vtb = (unsigned short*)(ws);
    unsigned short* Xk  = (unsigned short*)(ws + (8u << 20));
    unsigned short* Ob  = (unsigned short*)(ws + (8u << 20));
    unsigned short* Xv  = (unsigned short*)(ws + (16u << 20));
    unsigned short* Wqb = (unsigned short*)(ws + (24u << 20));
    unsigned short* Wkb = (unsigned short*)(ws + (26u << 20));
    unsigned short* Wvb = (unsigned short*)(ws + (28u << 20));
    unsigned short* Wob = (unsigned short*)(ws + (30u << 20));
    unsigned short* Qb  = (unsigned short*)(ws + (32u << 20));
    unsigned short* Kb  = (unsigned short*)(ws + (40u << 20));
    unsigned short* Vb  = (unsigned short*)(ws + (48u << 20));
    float* pO = (float*)(ws + (56u << 20));       // 32 MB (2 splits x 16 MB)
    float* pl = (float*)(ws + (88u << 20));       // 512 KB

    cvt3_act<<<dim3(3 * 2048), blk, 0, stream>>>(query, key, value, Xq, Xk, Xv);
    cvt4_w<<<dim3(4 * 512), blk, 0, stream>>>(Wq, Wk, Wv, Wo, Wqb, Wkb, Wvb, Wob);
    gemm_qkv<<<dim3(768), blk, 0, stream>>>(Xq, Xk, Xv, Wqb, Wkb, Wvb,
                                            bq, bk, bv, Qb, Kb, Vb, ALPHA_Q);
    transpose_v<<<dim3(1024), blk, 0, stream>>>(Vb, Vtb);
    if (ws_size >= (size_t)(89u * 1024u * 1024u)) {
      attn_kernel<2><<<dim3(2048), dim3(128), 0, stream>>>(Qb, Kb, Vtb, Ob, pO, pl);
      attn_combine<<<dim3(2048), blk, 0, stream>>>(pO, pl, Ob);
    } else {
      attn_kernel<1><<<dim3(1024), dim3(128), 0, stream>>>(Qb, Kb, Vtb, Ob, pO, pl);
    }
    gemm_bt64_f32<<<dim3(512), blk, 0, stream>>>(Ob, Wob, bo, (float*)d_out);
  } else {
    // ---- Path B: sequential (34 MB workspace) ----
    unsigned short* X   = (unsigned short*)(ws);
    unsigned short* Vtb = (unsigned short*)(ws);
    unsigned short* W   = (unsigned short*)(ws + 8388608);
    unsigned short* Qb  = (unsigned short*)(ws + 10485760);
    unsigned short* Kb  = (unsigned short*)(ws + 18874368);
    unsigned short* Vb  = (unsigned short*)(ws + 27262976);
    unsigned short* Ob  = (unsigned short*)(ws + 27262976);

    cvt_f32_bf16<<<dim3(ACT / 2048), blk, 0, stream>>>(query, X, ACT);
    cvt_f32_bf16<<<dim3(WEL / 2048), blk, 0, stream>>>(Wq, W, WEL);
    gemm_bt<0><<<dim3(256), blk, 0, stream>>>(X, W, bq, (void*)Qb, M, N, Kd, ALPHA_Q);

    cvt_f32_bf16<<<dim3(ACT / 2048), blk, 0, stream>>>(key, X, ACT);
    cvt_f32_bf16<<<dim3(WEL / 2048), blk, 0, stream>>>(Wk, W, WEL);
    gemm_bt<0><<<dim3(256), blk, 0, stream>>>(X, W, bk, (void*)Kb, M, N, Kd, 1.0f);

    cvt_f32_bf16<<<dim3(ACT / 2048), blk, 0, stream>>>(value, X, ACT);
    cvt_f32_bf16<<<dim3(WEL / 2048), blk, 0, stream>>>(Wv, W, WEL);
    gemm_bt<0><<<dim3(256), blk, 0, stream>>>(X, W, bv, (void*)Vb, M, N, Kd, 1.0f);

    transpose_v<<<dim3(1024), blk, 0, stream>>>(Vb, Vtb);
    cvt_f32_bf16<<<dim3(WEL / 2048), blk, 0, stream>>>(Wo, W, WEL);
    attn_kernel<1><<<dim3(1024), dim3(128), 0, stream>>>(Qb, Kb, Vtb, Ob, (float*)ws, (float*)ws);
    gemm_bt64_f32<<<dim3(512), blk, 0, stream>>>(Ob, W, bo, (float*)d_out);
  }
}

// Round 10
// 206.192 us; speedup vs baseline: 1.7950x; 1.0609x over previous
//
#include <hip/hip_runtime.h>
#include <stdint.h>

typedef __attribute__((ext_vector_type(4))) float f32x4;
typedef __attribute__((ext_vector_type(8))) __bf16 bf16x8;
typedef __attribute__((ext_vector_type(8))) unsigned short u16x8;

typedef __attribute__((address_space(1))) const unsigned int guint;
typedef __attribute__((address_space(3))) unsigned int luint;

#if __has_builtin(__builtin_amdgcn_exp2f)
#define EXP2(x) __builtin_amdgcn_exp2f(x)
#else
#define EXP2(x) exp2f(x)
#endif

__device__ __forceinline__ void gload_lds16(const void* g, void* l) {
  __builtin_amdgcn_global_load_lds((guint*)g, (luint*)l, 16, 0, 0);
}

__device__ __forceinline__ unsigned short f2bf(float f) {
  unsigned int u = __builtin_bit_cast(unsigned int, f);
  u += 0x7fffu + ((u >> 16) & 1u);   // RNE
  return (unsigned short)(u >> 16);
}

__device__ __forceinline__ void cvt8(const float* src, unsigned short* dst) {
  float4 a = *(const float4*)(src);
  float4 b = *(const float4*)(src + 4);
  u16x8 r;
  r[0] = f2bf(a.x); r[1] = f2bf(a.y); r[2] = f2bf(a.z); r[3] = f2bf(a.w);
  r[4] = f2bf(b.x); r[5] = f2bf(b.y); r[6] = f2bf(b.z); r[7] = f2bf(b.w);
  *(u16x8*)(dst) = r;
}

// ---------------- single fp32 -> bf16 convert (fallback path) ----------------
__global__ __launch_bounds__(256) void cvt_f32_bf16(const float* __restrict__ in,
                                                    unsigned short* __restrict__ out,
                                                    int n) {
  int i = ((int)blockIdx.x * 256 + (int)threadIdx.x) * 8;
  if (i >= n) return;
  cvt8(in + i, out + i);
}

// ------- ALL 7 converts in one launch: 3 act x 2048 blocks + 4 w x 512 -------
__global__ __launch_bounds__(256) void cvt_all(
    const float* __restrict__ a0, const float* __restrict__ a1, const float* __restrict__ a2,
    const float* __restrict__ w0, const float* __restrict__ w1,
    const float* __restrict__ w2, const float* __restrict__ w3,
    unsigned short* __restrict__ o0, unsigned short* __restrict__ o1,
    unsigned short* __restrict__ o2,
    unsigned short* __restrict__ p0, unsigned short* __restrict__ p1,
    unsigned short* __restrict__ p2, unsigned short* __restrict__ p3) {
  int b = (int)blockIdx.x;
  const float* src;
  unsigned short* dst;
  int i;
  if (b < 6144) {
    int s = b >> 11;
    i = ((b & 2047) * 256 + (int)threadIdx.x) * 8;
    src = (s == 0) ? a0 : (s == 1) ? a1 : a2;
    dst = (s == 0) ? o0 : (s == 1) ? o1 : o2;
  } else {
    int c = b - 6144;
    int s = c >> 9;
    i = ((c & 511) * 256 + (int)threadIdx.x) * 8;
    src = (s == 0) ? w0 : (s == 1) ? w1 : (s == 2) ? w2 : w3;
    dst = (s == 0) ? p0 : (s == 1) ? p1 : (s == 2) ? p2 : p3;
  }
  cvt8(src + i, dst + i);
}

// ---------------- GEMM: C[M,N] = A[M,K] @ Bw[N,K]^T, 128x128 tile ----------------
template <int OUTF32>
__global__ __launch_bounds__(256) void gemm_bt(const unsigned short* __restrict__ A,
                                               const unsigned short* __restrict__ Bw,
                                               const float* __restrict__ bias,
                                               void* __restrict__ Cout,
                                               int M, int N, int K, float alpha) {
  __shared__ __align__(16) unsigned short As[128 * 32];
  __shared__ __align__(16) unsigned short Bs[128 * 32];
  const int tid = threadIdx.x;
  const int lane = tid & 63;
  const int wave = tid >> 6;
  const int wr = wave >> 1, wc = wave & 1;
  const int ln = lane & 15, lg = lane >> 4;

  const int nwg = (int)gridDim.x;
  int bid = (int)blockIdx.x;
  int swz = (bid & 7) * (nwg >> 3) + (bid >> 3);
  const int nbn = N >> 7;
  const int bm = swz / nbn, bn = swz % nbn;
  const int row0 = bm << 7, col0 = bn << 7;

  f32x4 acc[4][4] = {};

  for (int kt = 0; kt < K; kt += 32) {
    __syncthreads();
#pragma unroll
    for (int c = 0; c < 2; ++c) {
      int idx = c * 256 + tid;
      int r = idx >> 2, cg = idx & 3;
      gload_lds16(A + (row0 + r) * K + kt + cg * 8, &As[idx * 8]);
    }
#pragma unroll
    for (int c = 0; c < 2; ++c) {
      int idx = c * 256 + tid;
      int r = idx >> 2, cg = idx & 3;
      gload_lds16(Bw + (col0 + r) * K + kt + cg * 8, &Bs[idx * 8]);
    }
    __syncthreads();
    bf16x8 a[4], b[4];
#pragma unroll
    for (int mi = 0; mi < 4; ++mi)
      a[mi] = *(const bf16x8*)&As[(wr * 64 + mi * 16 + ln) * 32 + lg * 8];
#pragma unroll
    for (int ni = 0; ni < 4; ++ni)
      b[ni] = *(const bf16x8*)&Bs[(wc * 64 + ni * 16 + ln) * 32 + lg * 8];
#pragma unroll
    for (int mi = 0; mi < 4; ++mi)
#pragma unroll
      for (int ni = 0; ni < 4; ++ni)
        acc[mi][ni] = __builtin_amdgcn_mfma_f32_16x16x32_bf16(a[mi], b[ni], acc[mi][ni], 0, 0, 0);
  }

#pragma unroll
  for (int mi = 0; mi < 4; ++mi)
#pragma unroll
    for (int ni = 0; ni < 4; ++ni) {
      int n = col0 + wc * 64 + ni * 16 + ln;
      float bv = bias[n];
#pragma unroll
      for (int r = 0; r < 4; ++r) {
        int m = row0 + wr * 64 + mi * 16 + lg * 4 + r;
        float v = (acc[mi][ni][r] + bv) * alpha;
        if (OUTF32)
          ((float*)Cout)[(size_t)m * N + n] = v;
        else
          ((unsigned short*)Cout)[(size_t)m * N + n] = f2bf(v);
      }
    }
}

// ------- Batched QKV GEMM: 3 x [4096,1024]x[1024,1024]^T, grid 768, 3 blk/CU -------
__global__ __launch_bounds__(256) void gemm_qkv(
    const unsigned short* __restrict__ Aq, const unsigned short* __restrict__ Ak,
    const unsigned short* __restrict__ Av,
    const unsigned short* __restrict__ Wqb, const unsigned short* __restrict__ Wkb,
    const unsigned short* __restrict__ Wvb,
    const float* __restrict__ bqp, const float* __restrict__ bkp,
    const float* __restrict__ bvp,
    unsigned short* __restrict__ Cq, unsigned short* __restrict__ Ck,
    unsigned short* __restrict__ Cv, float alphaQ) {
  const int K = 1024, N = 1024;
  __shared__ __align__(16) unsigned short As[128 * 32];
  __shared__ __align__(16) unsigned short Bs[128 * 32];
  const int tid = threadIdx.x;
  const int lane = tid & 63;
  const int wave = tid >> 6;
  const int wr = wave >> 1, wc = wave & 1;
  const int ln = lane & 15, lg = lane >> 4;

  int bid = (int)blockIdx.x;
  int swz = (bid & 7) * 96 + (bid >> 3);   // nwg=768
  const int bm = swz >> 3, bn = swz & 7;
  const int batch = bm >> 5, bmL = bm & 31;
  const unsigned short* A;
  const unsigned short* Bw;
  const float* bias;
  unsigned short* C;
  float alpha;
  if (batch == 0)      { A = Aq; Bw = Wqb; bias = bqp; C = Cq; alpha = alphaQ; }
  else if (batch == 1) { A = Ak; Bw = Wkb; bias = bkp; C = Ck; alpha = 1.0f; }
  else                 { A = Av; Bw = Wvb; bias = bvp; C = Cv; alpha = 1.0f; }
  const int row0 = bmL << 7, col0 = bn << 7;

  f32x4 acc[4][4] = {};

  for (int kt = 0; kt < K; kt += 32) {
    __syncthreads();
#pragma unroll
    for (int c = 0; c < 2; ++c) {
      int idx = c * 256 + tid;
      int r = idx >> 2, cg = idx & 3;
      gload_lds16(A + (row0 + r) * K + kt + cg * 8, &As[idx * 8]);
    }
#pragma unroll
    for (int c = 0; c < 2; ++c) {
      int idx = c * 256 + tid;
      int r = idx >> 2, cg = idx & 3;
      gload_lds16(Bw + (col0 + r) * K + kt + cg * 8, &Bs[idx * 8]);
    }
    __syncthreads();
    bf16x8 a[4], b[4];
#pragma unroll
    for (int mi = 0; mi < 4; ++mi)
      a[mi] = *(const bf16x8*)&As[(wr * 64 + mi * 16 + ln) * 32 + lg * 8];
#pragma unroll
    for (int ni = 0; ni < 4; ++ni)
      b[ni] = *(const bf16x8*)&Bs[(wc * 64 + ni * 16 + ln) * 32 + lg * 8];
#pragma unroll
    for (int mi = 0; mi < 4; ++mi)
#pragma unroll
      for (int ni = 0; ni < 4; ++ni)
        acc[mi][ni] = __builtin_amdgcn_mfma_f32_16x16x32_bf16(a[mi], b[ni], acc[mi][ni], 0, 0, 0);
  }

#pragma unroll
  for (int mi = 0; mi < 4; ++mi)
#pragma unroll
    for (int ni = 0; ni < 4; ++ni) {
      int n = col0 + wc * 64 + ni * 16 + ln;
      float bv = bias[n];
#pragma unroll
      for (int r = 0; r < 4; ++r) {
        int m = row0 + wr * 64 + mi * 16 + lg * 4 + r;
        C[(size_t)m * N + n] = f2bf((acc[mi][ni][r] + bv) * alpha);
      }
    }
}

// ------- Out-proj GEMM: 128x64 tile, f32 out, grid 512 (2 blk/CU) -------
__global__ __launch_bounds__(256) void gemm_bt64_f32(const unsigned short* __restrict__ A,
                                                     const unsigned short* __restrict__ Bw,
                                                     const float* __restrict__ bias,
                                                     float* __restrict__ Cout) {
  const int K = 1024, N = 1024;
  __shared__ __align__(16) unsigned short As[128 * 32];
  __shared__ __align__(16) unsigned short Bs[64 * 32];
  const int tid = threadIdx.x;
  const int lane = tid & 63;
  const int wr = tid >> 6;          // wave = 32-row strip
  const int ln = lane & 15, lg = lane >> 4;

  int bid = (int)blockIdx.x;
  int swz = (bid & 7) * 64 + (bid >> 3);   // nwg=512
  const int bm = swz >> 4, bn = swz & 15;
  const int row0 = bm << 7, col0 = bn << 6;

  f32x4 acc[2][4] = {};

  for (int kt = 0; kt < K; kt += 32) {
    __syncthreads();
#pragma unroll
    for (int c = 0; c < 2; ++c) {
      int idx = c * 256 + tid;
      int r = idx >> 2, cg = idx & 3;
      gload_lds16(A + (row0 + r) * K + kt + cg * 8, &As[idx * 8]);
    }
    {
      int r = tid >> 2, cg = tid & 3;
      gload_lds16(Bw + (col0 + r) * K + kt + cg * 8, &Bs[tid * 8]);
    }
    __syncthreads();
    bf16x8 a[2], b[4];
#pragma unroll
    for (int mi = 0; mi < 2; ++mi)
      a[mi] = *(const bf16x8*)&As[(wr * 32 + mi * 16 + ln) * 32 + lg * 8];
#pragma unroll
    for (int ni = 0; ni < 4; ++ni)
      b[ni] = *(const bf16x8*)&Bs[(ni * 16 + ln) * 32 + lg * 8];
#pragma unroll
    for (int mi = 0; mi < 2; ++mi)
#pragma unroll
      for (int ni = 0; ni < 4; ++ni)
        acc[mi][ni] = __builtin_amdgcn_mfma_f32_16x16x32_bf16(a[mi], b[ni], acc[mi][ni], 0, 0, 0);
  }

#pragma unroll
  for (int mi = 0; mi < 2; ++mi)
#pragma unroll
    for (int ni = 0; ni < 4; ++ni) {
      int n = col0 + ni * 16 + ln;
      float bv = bias[n];
#pragma unroll
      for (int r = 0; r < 4; ++r) {
        int m = row0 + wr * 32 + mi * 16 + lg * 4 + r;
        Cout[(size_t)m * N + n] = acc[mi][ni][r] + bv;
      }
    }
}

// ---------------- V transpose per head: [32][2048][64] -> [32][64][2048] ----
// Output keys PERMUTED within each 64-key tile to match the P-store layout:
//   storage pos(k) = (k>>5)*32 + (k&15)*2 + ((k>>4)&1)   [validated R6-R8]
__global__ __launch_bounds__(256) void transpose_v(const unsigned short* __restrict__ V,
                                                   unsigned short* __restrict__ Vt) {
  __shared__ unsigned short t[64][65];
  const int g = (int)blockIdx.x >> 5;
  const int kt = (int)blockIdx.x & 31;
  const int tid = threadIdx.x;
  const int base = g << 17;
#pragma unroll
  for (int h = 0; h < 2; ++h) {
    int key = (tid >> 3) + h * 32, d0 = (tid & 7) * 8;
    u16x8 v = *(const u16x8*)(V + base + (kt * 64 + key) * 64 + d0);
#pragma unroll
    for (int j = 0; j < 8; ++j) t[d0 + j][key] = v[j];
  }
  __syncthreads();
  {
    int d = tid >> 2, q3 = tid & 3;
    u16x8 r0, r1;
#pragma unroll
    for (int i = 0; i < 8; ++i) {
      int k = (q3 >> 1) * 32 + (i & 1) * 16 + (q3 & 1) * 8 + (i >> 1);
      r0[i] = t[d][k];
    }
#pragma unroll
    for (int i = 8; i < 16; ++i) {
      int k = (q3 >> 1) * 32 + (i & 1) * 16 + (q3 & 1) * 8 + (i >> 1);
      r1[i - 8] = t[d][k];
    }
    unsigned short* o = Vt + base + d * 2048 + kt * 64 + q3 * 16;
    *(u16x8*)(o) = r0;
    *(u16x8*)(o + 8) = r1;
  }
}

// ---------------- Flash attention over 32 heads of [2048,64] ----------------
// Q pre-scaled by (1/8)*log2(e): p = exp2(S), no max tracking.
// R10: proven R8 NSPLIT=1 structure (16x16 MFMA, parity-LDS P, conflict-free
// 16B-granule XOR swizzle). Split-KV dropped (falsified R8). NEW: per-block
// KV start rotation (rot+i)&31 — exact (l, acc are order-invariant sums);
// de-phases blocks / spreads L2 if attn is lockstep-contention-bound.
__global__ __launch_bounds__(128) void attn_kernel(const unsigned short* __restrict__ Q,
                                                   const unsigned short* __restrict__ Km,
                                                   const unsigned short* __restrict__ Vt,
                                                   unsigned short* __restrict__ O) {
  __shared__ __align__(16) unsigned short Ps[2][2][32 * 64];  // [wave][parity]
  const int tid = threadIdx.x;
  const int lane = tid & 63, wave = tid >> 6;
  const int ln = lane & 15, lg = lane >> 4;

  const int bid = (int)blockIdx.x;
  const int g = (bid & 7) + ((bid >> 8) << 3);
  const int qt = (bid >> 3) & 31;
  const int base = g << 17;
  const int qrow0 = qt * 64 + wave * 32;
  const int rot = (bid * 7) & 31;

  bf16x8 aq[2][2];
#pragma unroll
  for (int mb = 0; mb < 2; ++mb)
#pragma unroll
    for (int kb = 0; kb < 2; ++kb)
      aq[mb][kb] = *(const bf16x8*)(Q + base + (qrow0 + mb * 16 + ln) * 64 + kb * 32 + lg * 8);

  float l_p[2][4] = {};
  f32x4 acc_o[2][4] = {};
  f32x4 s[2][4];
  bf16x8 Kf[2][4], Vf[2][4], ap[2][2];

  auto loadK = [&](int kv) {
    const unsigned short* Kt = Km + base + (kv << 12);
#pragma unroll
    for (int kb = 0; kb < 2; ++kb)
#pragma unroll
      for (int nb = 0; nb < 4; ++nb)
        Kf[kb][nb] = *(const bf16x8*)(Kt + (nb * 16 + ln) * 64 + kb * 32 + lg * 8);
  };
  auto loadV = [&](int kv) {
    const unsigned short* Vp = Vt + base + kv * 64;
#pragma unroll
    for (int kb = 0; kb < 2; ++kb)
#pragma unroll
      for (int nd = 0; nd < 4; ++nd)
        Vf[kb][nd] = *(const bf16x8*)(Vp + (nd * 16 + ln) * 2048 + kb * 32 + lg * 8);
  };
  auto QK = [&]() {
#pragma unroll
    for (int mb = 0; mb < 2; ++mb)
#pragma unroll
      for (int nb = 0; nb < 4; ++nb)
        s[mb][nb] = (f32x4){0.f, 0.f, 0.f, 0.f};
    __builtin_amdgcn_s_setprio(1);
#pragma unroll
    for (int kb = 0; kb < 2; ++kb)
#pragma unroll
      for (int nb = 0; nb < 4; ++nb)
#pragma unroll
        for (int mb = 0; mb < 2; ++mb)
          s[mb][nb] = __builtin_amdgcn_mfma_f32_16x16x32_bf16(aq[mb][kb], Kf[kb][nb], s[mb][nb], 0, 0, 0);
    __builtin_amdgcn_s_setprio(0);
  };
  auto PVload = [&](int parR) {
    const unsigned short* PR = &Ps[wave][parR][0];
#pragma unroll
    for (int kb = 0; kb < 2; ++kb)
#pragma unroll
      for (int mb = 0; mb < 2; ++mb) {
        int row = mb * 16 + ln;
        ap[kb][mb] = *(const bf16x8*)&PR[row * 64 +
                                        (((kb * 16 + lg * 4) ^ ((row & 7) << 2)) << 1)];
      }
  };
  auto SM = [&](int parW) {
    unsigned int* PW = (unsigned int*)&Ps[wave][parW][0];
#pragma unroll
    for (int mb = 0; mb < 2; ++mb)
#pragma unroll
      for (int r = 0; r < 4; ++r) {
        int q = mb * 16 + lg * 4 + r;
        float p0 = EXP2(s[mb][0][r]);
        float p1 = EXP2(s[mb][1][r]);
        float p2 = EXP2(s[mb][2][r]);
        float p3 = EXP2(s[mb][3][r]);
        unsigned int d0, d1;
        asm("v_cvt_pk_bf16_f32 %0, %1, %2" : "=v"(d0) : "v"(p0), "v"(p1));
        asm("v_cvt_pk_bf16_f32 %0, %1, %2" : "=v"(d1) : "v"(p2), "v"(p3));
        int dwb = q * 32;
        int x = (q & 7) << 2;
        PW[dwb + (ln ^ x)] = d0;            // keys (ln, ln+16)
        PW[dwb + ((16 + ln) ^ x)] = d1;     // keys (32+ln, 48+ln)
        l_p[mb][r] += (p0 + p1) + (p2 + p3);
      }
  };
  auto PVmma = [&]() {
    __builtin_amdgcn_s_setprio(1);
#pragma unroll
    for (int kb = 0; kb < 2; ++kb)
#pragma unroll
      for (int nd = 0; nd < 4; ++nd)
#pragma unroll
        for (int mb = 0; mb < 2; ++mb)
          acc_o[mb][nd] = __builtin_amdgcn_mfma_f32_16x16x32_bf16(ap[kb][mb], Vf[kb][nd], acc_o[mb][nd], 0, 0, 0);
    __builtin_amdgcn_s_setprio(0);
  };

  // prologue: first tile (rotated start)
  loadK(rot); loadV(rot);
  QK();
  loadK((rot + 1) & 31);
  SM(0);
  // steady state: QK(i) | prefetch K(i+1) | PVload(i-1) | SM(i) | PVmma(i-1) | loadV(i)
  for (int i = 1; i < 32; ++i) {
    QK();
    loadK((rot + (i + 1 < 32 ? i + 1 : 31)) & 31);
    PVload((i - 1) & 1);
    SM(i & 1);
    PVmma();
    loadV((rot + i) & 31);
  }
  PVload(1);
  PVmma();

  // epilogue: reduce l over the 16-lane key group, divide, store
#pragma unroll
  for (int mb = 0; mb < 2; ++mb)
#pragma unroll
    for (int r = 0; r < 4; ++r) {
      float ls = l_p[mb][r];
      ls += __shfl_xor(ls, 1);
      ls += __shfl_xor(ls, 2);
      ls += __shfl_xor(ls, 4);
      ls += __shfl_xor(ls, 8);
      float inv = 1.f / ls;
      int row = qrow0 + mb * 16 + lg * 4 + r;
#pragma unroll
      for (int nd = 0; nd < 4; ++nd)
        O[base + row * 64 + nd * 16 + ln] = f2bf(acc_o[mb][nd][r] * inv);
    }
}

// ---------------- launch ----------------
extern "C" void kernel_launch(void* const* d_in, const int* in_sizes, int n_in,
                              void* d_out, int out_size, void* d_ws, size_t ws_size,
                              hipStream_t stream) {
  const float* query = (const float*)d_in[0];
  const float* key   = (const float*)d_in[1];
  const float* value = (const float*)d_in[2];
  const float* Wq = (const float*)d_in[3];
  const float* bq = (const float*)d_in[4];
  const float* Wk = (const float*)d_in[5];
  const float* bk = (const float*)d_in[6];
  const float* Wv = (const float*)d_in[7];
  const float* bv = (const float*)d_in[8];
  const float* Wo = (const float*)d_in[9];
  const float* bo = (const float*)d_in[10];

  const int ACT = 4096 * 1024;
  const int WEL = 1024 * 1024;
  const int M = 4096, N = 1024, Kd = 1024;
  const float ALPHA_Q = 0.125f * 1.44269504f;   // 1/sqrt(64) * log2(e)

  char* ws = (char*)d_ws;
  dim3 blk(256);

  if (ws_size >= (size_t)(56u * 1024u * 1024u)) {
    // ---- Path A: merged converts + batched QKV + attention ----
    unsigned short* Xq  = (unsigned short*)(ws);
    unsigned short* Vtb = (unsigned short*)(ws);
    unsigned short* Xk  = (unsigned short*)(ws + (8u << 20));
    unsigned short* Ob  = (unsigned short*)(ws + (8u << 20));
    unsigned short* Xv  = (unsigned short*)(ws + (16u << 20));
    unsigned short* Wqb = (unsigned short*)(ws + (24u << 20));
    unsigned short* Wkb = (unsigned short*)(ws + (26u << 20));
    unsigned short* Wvb = (unsigned short*)(ws + (28u << 20));
    unsigned short* Wob = (unsigned short*)(ws + (30u << 20));
    unsigned short* Qb  = (unsigned short*)(ws + (32u << 20));
    unsigned short* Kb  = (unsigned short*)(ws + (40u << 20));
    unsigned short* Vb  = (unsigned short*)(ws + (48u << 20));

    cvt_all<<<dim3(8192), blk, 0, stream>>>(query, key, value, Wq, Wk, Wv, Wo,
                                            Xq, Xk, Xv, Wqb, Wkb, Wvb, Wob);
    gemm_qkv<<<dim3(768), blk, 0, stream>>>(Xq, Xk, Xv, Wqb, Wkb, Wvb,
                                            bq, bk, bv, Qb, Kb, Vb, ALPHA_Q);
    transpose_v<<<dim3(1024), blk, 0, stream>>>(Vb, Vtb);
    attn_kernel<<<dim3(1024), dim3(128), 0, stream>>>(Qb, Kb, Vtb, Ob);
    gemm_bt64_f32<<<dim3(512), blk, 0, stream>>>(Ob, Wob, bo, (float*)d_out);
  } else {
    // ---- Path B: sequential (34 MB workspace) ----
    unsigned short* X   = (unsigned short*)(ws);
    unsigned short* Vtb = (unsigned short*)(ws);
    unsigned short* W   = (unsigned short*)(ws + 8388608);
    unsigned short* Qb  = (unsigned short*)(ws + 10485760);
    unsigned short* Kb  = (unsigned short*)(ws + 18874368);
    unsigned short* Vb  = (unsigned short*)(ws + 27262976);
    unsigned short* Ob  = (unsigned short*)(ws + 27262976);

    cvt_f32_bf16<<<dim3(ACT / 2048), blk, 0, stream>>>(query, X, ACT);
    cvt_f32_bf16<<<dim3(WEL / 2048), blk, 0, stream>>>(Wq, W, WEL);
    gemm_bt<0><<<dim3(256), blk, 0, stream>>>(X, W, bq, (void*)Qb, M, N, Kd, ALPHA_Q);

    cvt_f32_bf16<<<dim3(ACT / 2048), blk, 0, stream>>>(key, X, ACT);
    cvt_f32_bf16<<<dim3(WEL / 2048), blk, 0, stream>>>(Wk, W, WEL);
    gemm_bt<0><<<dim3(256), blk, 0, stream>>>(X, W, bk, (void*)Kb, M, N, Kd, 1.0f);

    cvt_f32_bf16<<<dim3(ACT / 2048), blk, 0, stream>>>(value, X, ACT);
    cvt_f32_bf16<<<dim3(WEL / 2048), blk, 0, stream>>>(Wv, W, WEL);
    gemm_bt<0><<<dim3(256), blk, 0, stream>>>(X, W, bv, (void*)Vb, M, N, Kd, 1.0f);

    transpose_v<<<dim3(1024), blk, 0, stream>>>(Vb, Vtb);
    cvt_f32_bf16<<<dim3(WEL / 2048), blk, 0, stream>>>(Wo, W, WEL);
    attn_kernel<<<dim3(1024), dim3(128), 0, stream>>>(Qb, Kb, Vtb, Ob);
    gemm_bt64_f32<<<dim3(512), blk, 0, stream>>>(Ob, W, bo, (float*)d_out);
  }
}

// Round 11
// 139.049 us; speedup vs baseline: 2.6617x; 1.4829x over previous
//
#include <hip/hip_runtime.h>
#include <stdint.h>

typedef __attribute__((ext_vector_type(4))) float f32x4;
typedef __attribute__((ext_vector_type(8))) __bf16 bf16x8;
typedef __attribute__((ext_vector_type(8))) unsigned short u16x8;

typedef __attribute__((address_space(1))) const unsigned int guint;
typedef __attribute__((address_space(3))) unsigned int luint;

#if __has_builtin(__builtin_amdgcn_exp2f)
#define EXP2(x) __builtin_amdgcn_exp2f(x)
#else
#define EXP2(x) exp2f(x)
#endif

__device__ __forceinline__ void gload_lds16(const void* g, void* l) {
  __builtin_amdgcn_global_load_lds((guint*)g, (luint*)l, 16, 0, 0);
}

__device__ __forceinline__ unsigned short f2bf(float f) {
  unsigned int u = __builtin_bit_cast(unsigned int, f);
  u += 0x7fffu + ((u >> 16) & 1u);   // RNE
  return (unsigned short)(u >> 16);
}

__device__ __forceinline__ void cvt8(const float* src, unsigned short* dst) {
  float4 a = *(const float4*)(src);
  float4 b = *(const float4*)(src + 4);
  u16x8 r;
  r[0] = f2bf(a.x); r[1] = f2bf(a.y); r[2] = f2bf(a.z); r[3] = f2bf(a.w);
  r[4] = f2bf(b.x); r[5] = f2bf(b.y); r[6] = f2bf(b.z); r[7] = f2bf(b.w);
  *(u16x8*)(dst) = r;
}

// ---------------- single fp32 -> bf16 convert (fallback path) ----------------
__global__ __launch_bounds__(256) void cvt_f32_bf16(const float* __restrict__ in,
                                                    unsigned short* __restrict__ out,
                                                    int n) {
  int i = ((int)blockIdx.x * 256 + (int)threadIdx.x) * 8;
  if (i >= n) return;
  cvt8(in + i, out + i);
}

// ------- ALL 7 converts in one launch: 3 act x 2048 blocks + 4 w x 512 -------
__global__ __launch_bounds__(256) void cvt_all(
    const float* __restrict__ a0, const float* __restrict__ a1, const float* __restrict__ a2,
    const float* __restrict__ w0, const float* __restrict__ w1,
    const float* __restrict__ w2, const float* __restrict__ w3,
    unsigned short* __restrict__ o0, unsigned short* __restrict__ o1,
    unsigned short* __restrict__ o2,
    unsigned short* __restrict__ p0, unsigned short* __restrict__ p1,
    unsigned short* __restrict__ p2, unsigned short* __restrict__ p3) {
  int b = (int)blockIdx.x;
  const float* src;
  unsigned short* dst;
  int i;
  if (b < 6144) {
    int s = b >> 11;
    i = ((b & 2047) * 256 + (int)threadIdx.x) * 8;
    src = (s == 0) ? a0 : (s == 1) ? a1 : a2;
    dst = (s == 0) ? o0 : (s == 1) ? o1 : o2;
  } else {
    int c = b - 6144;
    int s = c >> 9;
    i = ((c & 511) * 256 + (int)threadIdx.x) * 8;
    src = (s == 0) ? w0 : (s == 1) ? w1 : (s == 2) ? w2 : w3;
    dst = (s == 0) ? p0 : (s == 1) ? p1 : (s == 2) ? p2 : p3;
  }
  cvt8(src + i, dst + i);
}

// ---------------- GEMM: C[M,N] = A[M,K] @ Bw[N,K]^T, 128x128 tile ----------------
template <int OUTF32>
__global__ __launch_bounds__(256) void gemm_bt(const unsigned short* __restrict__ A,
                                               const unsigned short* __restrict__ Bw,
                                               const float* __restrict__ bias,
                                               void* __restrict__ Cout,
                                               int M, int N, int K, float alpha) {
  __shared__ __align__(16) unsigned short As[128 * 32];
  __shared__ __align__(16) unsigned short Bs[128 * 32];
  const int tid = threadIdx.x;
  const int lane = tid & 63;
  const int wave = tid >> 6;
  const int wr = wave >> 1, wc = wave & 1;
  const int ln = lane & 15, lg = lane >> 4;

  const int nwg = (int)gridDim.x;
  int bid = (int)blockIdx.x;
  int swz = (bid & 7) * (nwg >> 3) + (bid >> 3);
  const int nbn = N >> 7;
  const int bm = swz / nbn, bn = swz % nbn;
  const int row0 = bm << 7, col0 = bn << 7;

  f32x4 acc[4][4] = {};

  for (int kt = 0; kt < K; kt += 32) {
    __syncthreads();
#pragma unroll
    for (int c = 0; c < 2; ++c) {
      int idx = c * 256 + tid;
      int r = idx >> 2, cg = idx & 3;
      gload_lds16(A + (row0 + r) * K + kt + cg * 8, &As[idx * 8]);
    }
#pragma unroll
    for (int c = 0; c < 2; ++c) {
      int idx = c * 256 + tid;
      int r = idx >> 2, cg = idx & 3;
      gload_lds16(Bw + (col0 + r) * K + kt + cg * 8, &Bs[idx * 8]);
    }
    __syncthreads();
    bf16x8 a[4], b[4];
#pragma unroll
    for (int mi = 0; mi < 4; ++mi)
      a[mi] = *(const bf16x8*)&As[(wr * 64 + mi * 16 + ln) * 32 + lg * 8];
#pragma unroll
    for (int ni = 0; ni < 4; ++ni)
      b[ni] = *(const bf16x8*)&Bs[(wc * 64 + ni * 16 + ln) * 32 + lg * 8];
#pragma unroll
    for (int mi = 0; mi < 4; ++mi)
#pragma unroll
      for (int ni = 0; ni < 4; ++ni)
        acc[mi][ni] = __builtin_amdgcn_mfma_f32_16x16x32_bf16(a[mi], b[ni], acc[mi][ni], 0, 0, 0);
  }

#pragma unroll
  for (int mi = 0; mi < 4; ++mi)
#pragma unroll
    for (int ni = 0; ni < 4; ++ni) {
      int n = col0 + wc * 64 + ni * 16 + ln;
      float bv = bias[n];
#pragma unroll
      for (int r = 0; r < 4; ++r) {
        int m = row0 + wr * 64 + mi * 16 + lg * 4 + r;
        float v = (acc[mi][ni][r] + bv) * alpha;
        if (OUTF32)
          ((float*)Cout)[(size_t)m * N + n] = v;
        else
          ((unsigned short*)Cout)[(size_t)m * N + n] = f2bf(v);
      }
    }
}

// ------- Batched QKV GEMM: 3 x [4096,1024]x[1024,1024]^T, grid 768, 3 blk/CU -------
__global__ __launch_bounds__(256) void gemm_qkv(
    const unsigned short* __restrict__ Aq, const unsigned short* __restrict__ Ak,
    const unsigned short* __restrict__ Av,
    const unsigned short* __restrict__ Wqb, const unsigned short* __restrict__ Wkb,
    const unsigned short* __restrict__ Wvb,
    const float* __restrict__ bqp, const float* __restrict__ bkp,
    const float* __restrict__ bvp,
    unsigned short* __restrict__ Cq, unsigned short* __restrict__ Ck,
    unsigned short* __restrict__ Cv, float alphaQ) {
  const int K = 1024, N = 1024;
  __shared__ __align__(16) unsigned short As[128 * 32];
  __shared__ __align__(16) unsigned short Bs[128 * 32];
  const int tid = threadIdx.x;
  const int lane = tid & 63;
  const int wave = tid >> 6;
  const int wr = wave >> 1, wc = wave & 1;
  const int ln = lane & 15, lg = lane >> 4;

  int bid = (int)blockIdx.x;
  int swz = (bid & 7) * 96 + (bid >> 3);   // nwg=768
  const int bm = swz >> 3, bn = swz & 7;
  const int batch = bm >> 5, bmL = bm & 31;
  const unsigned short* A;
  const unsigned short* Bw;
  const float* bias;
  unsigned short* C;
  float alpha;
  if (batch == 0)      { A = Aq; Bw = Wqb; bias = bqp; C = Cq; alpha = alphaQ; }
  else if (batch == 1) { A = Ak; Bw = Wkb; bias = bkp; C = Ck; alpha = 1.0f; }
  else                 { A = Av; Bw = Wvb; bias = bvp; C = Cv; alpha = 1.0f; }
  const int row0 = bmL << 7, col0 = bn << 7;

  f32x4 acc[4][4] = {};

  for (int kt = 0; kt < K; kt += 32) {
    __syncthreads();
#pragma unroll
    for (int c = 0; c < 2; ++c) {
      int idx = c * 256 + tid;
      int r = idx >> 2, cg = idx & 3;
      gload_lds16(A + (row0 + r) * K + kt + cg * 8, &As[idx * 8]);
    }
#pragma unroll
    for (int c = 0; c < 2; ++c) {
      int idx = c * 256 + tid;
      int r = idx >> 2, cg = idx & 3;
      gload_lds16(Bw + (col0 + r) * K + kt + cg * 8, &Bs[idx * 8]);
    }
    __syncthreads();
    bf16x8 a[4], b[4];
#pragma unroll
    for (int mi = 0; mi < 4; ++mi)
      a[mi] = *(const bf16x8*)&As[(wr * 64 + mi * 16 + ln) * 32 + lg * 8];
#pragma unroll
    for (int ni = 0; ni < 4; ++ni)
      b[ni] = *(const bf16x8*)&Bs[(wc * 64 + ni * 16 + ln) * 32 + lg * 8];
#pragma unroll
    for (int mi = 0; mi < 4; ++mi)
#pragma unroll
      for (int ni = 0; ni < 4; ++ni)
        acc[mi][ni] = __builtin_amdgcn_mfma_f32_16x16x32_bf16(a[mi], b[ni], acc[mi][ni], 0, 0, 0);
  }

#pragma unroll
  for (int mi = 0; mi < 4; ++mi)
#pragma unroll
    for (int ni = 0; ni < 4; ++ni) {
      int n = col0 + wc * 64 + ni * 16 + ln;
      float bv = bias[n];
#pragma unroll
      for (int r = 0; r < 4; ++r) {
        int m = row0 + wr * 64 + mi * 16 + lg * 4 + r;
        C[(size_t)m * N + n] = f2bf((acc[mi][ni][r] + bv) * alpha);
      }
    }
}

// ------- Out-proj GEMM: 128x64 tile, f32 out, grid 512 (2 blk/CU) -------
__global__ __launch_bounds__(256) void gemm_bt64_f32(const unsigned short* __restrict__ A,
                                                     const unsigned short* __restrict__ Bw,
                                                     const float* __restrict__ bias,
                                                     float* __restrict__ Cout) {
  const int K = 1024, N = 1024;
  __shared__ __align__(16) unsigned short As[128 * 32];
  __shared__ __align__(16) unsigned short Bs[64 * 32];
  const int tid = threadIdx.x;
  const int lane = tid & 63;
  const int wr = tid >> 6;          // wave = 32-row strip
  const int ln = lane & 15, lg = lane >> 4;

  int bid = (int)blockIdx.x;
  int swz = (bid & 7) * 64 + (bid >> 3);   // nwg=512
  const int bm = swz >> 4, bn = swz & 15;
  const int row0 = bm << 7, col0 = bn << 6;

  f32x4 acc[2][4] = {};

  for (int kt = 0; kt < K; kt += 32) {
    __syncthreads();
#pragma unroll
    for (int c = 0; c < 2; ++c) {
      int idx = c * 256 + tid;
      int r = idx >> 2, cg = idx & 3;
      gload_lds16(A + (row0 + r) * K + kt + cg * 8, &As[idx * 8]);
    }
    {
      int r = tid >> 2, cg = tid & 3;
      gload_lds16(Bw + (col0 + r) * K + kt + cg * 8, &Bs[tid * 8]);
    }
    __syncthreads();
    bf16x8 a[2], b[4];
#pragma unroll
    for (int mi = 0; mi < 2; ++mi)
      a[mi] = *(const bf16x8*)&As[(wr * 32 + mi * 16 + ln) * 32 + lg * 8];
#pragma unroll
    for (int ni = 0; ni < 4; ++ni)
      b[ni] = *(const bf16x8*)&Bs[(ni * 16 + ln) * 32 + lg * 8];
#pragma unroll
    for (int mi = 0; mi < 2; ++mi)
#pragma unroll
      for (int ni = 0; ni < 4; ++ni)
        acc[mi][ni] = __builtin_amdgcn_mfma_f32_16x16x32_bf16(a[mi], b[ni], acc[mi][ni], 0, 0, 0);
  }

#pragma unroll
  for (int mi = 0; mi < 2; ++mi)
#pragma unroll
    for (int ni = 0; ni < 4; ++ni) {
      int n = col0 + ni * 16 + ln;
      float bv = bias[n];
#pragma unroll
      for (int r = 0; r < 4; ++r) {
        int m = row0 + wr * 32 + mi * 16 + lg * 4 + r;
        Cout[(size_t)m * N + n] = acc[mi][ni][r] + bv;
      }
    }
}

// ---------------- V transpose per head: [32][2048][64] -> [32][64][2048] ----
// Output keys PERMUTED within each 64-key tile to match the P-store layout:
//   storage pos(k) = (k>>5)*32 + (k&15)*2 + ((k>>4)&1)   [validated R6-R10]
__global__ __launch_bounds__(256) void transpose_v(const unsigned short* __restrict__ V,
                                                   unsigned short* __restrict__ Vt) {
  __shared__ unsigned short t[64][65];
  const int g = (int)blockIdx.x >> 5;
  const int kt = (int)blockIdx.x & 31;
  const int tid = threadIdx.x;
  const int base = g << 17;
#pragma unroll
  for (int h = 0; h < 2; ++h) {
    int key = (tid >> 3) + h * 32, d0 = (tid & 7) * 8;
    u16x8 v = *(const u16x8*)(V + base + (kt * 64 + key) * 64 + d0);
#pragma unroll
    for (int j = 0; j < 8; ++j) t[d0 + j][key] = v[j];
  }
  __syncthreads();
  {
    int d = tid >> 2, q3 = tid & 3;
    u16x8 r0, r1;
#pragma unroll
    for (int i = 0; i < 8; ++i) {
      int k = (q3 >> 1) * 32 + (i & 1) * 16 + (q3 & 1) * 8 + (i >> 1);
      r0[i] = t[d][k];
    }
#pragma unroll
    for (int i = 8; i < 16; ++i) {
      int k = (q3 >> 1) * 32 + (i & 1) * 16 + (q3 & 1) * 8 + (i >> 1);
      r1[i - 8] = t[d][k];
    }
    unsigned short* o = Vt + base + d * 2048 + kt * 64 + q3 * 16;
    *(u16x8*)(o) = r0;
    *(u16x8*)(o + 8) = r1;
  }
}

// ---------------- Flash attention over 32 heads of [2048,64] ----------------
// Q pre-scaled by (1/8)*log2(e): p = exp2(S), no max tracking (validated R4+).
// R11: GEMM-style global_load_lds staging of K/V into LDS, shared by 4 waves
// (128 q-rows/block, 512 blocks, 2/CU). Per-thread global loads per tile drop
// 16 -> 4. K/V LDS rows are 128B; reads use granule^=(row&7) XOR swizzle with
// PRE-SWIZZLED global source (rule: linear dest + inv-swz source + swz read).
// P path (swizzle, cvt_pk, permuted-V contraction) unchanged from R10 (proven).
__global__ __launch_bounds__(256) void attn_kernel(const unsigned short* __restrict__ Q,
                                                   const unsigned short* __restrict__ Km,
                                                   const unsigned short* __restrict__ Vt,
                                                   unsigned short* __restrict__ O) {
  __shared__ __align__(16) unsigned short Ks[64 * 64];
  __shared__ __align__(16) unsigned short Vs[64 * 64];
  __shared__ __align__(16) unsigned short Ps[4][32 * 64];
  const int tid = threadIdx.x;
  const int lane = tid & 63, wave = tid >> 6;
  const int ln = lane & 15, lg = lane >> 4;

  // XCD swizzle (nwg=512): 4 heads per XCD (2MB K+V, L2-resident)
  int bid = (int)blockIdx.x;
  int swz = (bid & 7) * 64 + (bid >> 3);
  const int g = swz >> 4, qt = swz & 15;
  const int base = g << 17;
  const int qrow0 = qt * 128 + wave * 32;

  bf16x8 aq[2][2];
#pragma unroll
  for (int mb = 0; mb < 2; ++mb)
#pragma unroll
    for (int kb = 0; kb < 2; ++kb)
      aq[mb][kb] = *(const bf16x8*)(Q + base + (qrow0 + mb * 16 + ln) * 64 + kb * 32 + lg * 8);

  float l_p[2][4] = {};
  f32x4 acc_o[2][4] = {};
  unsigned short* Pw = &Ps[wave][0];
  const int x7 = ln & 7;   // read-side granule XOR key (row&7 == ln&7 for row=nb*16+ln)

  for (int kv = 0; kv < 32; ++kv) {
    __syncthreads();
    // stage K tile [64 key][64 d] and V tile [64 d][64 key(permuted)]:
    // linear LDS dest slot s = row*8 + c16 (16B granules); source granule
    // pre-swizzled: c16 ^ (row&7). 2 K + 2 V gload_lds per thread.
#pragma unroll
    for (int c = 0; c < 2; ++c) {
      int slot = c * 256 + tid;
      int row = slot >> 3, c16 = slot & 7;
      int sg = (c16 ^ (row & 7)) * 8;
      gload_lds16(Km + base + ((kv * 64 + row) << 6) + sg, &Ks[slot * 8]);
      gload_lds16(Vt + base + row * 2048 + kv * 64 + sg, &Vs[slot * 8]);
    }
    __syncthreads();

    // ---- S = Q @ K^T, K-frags from swizzled LDS ----
    f32x4 s[2][4] = {};
    __builtin_amdgcn_s_setprio(1);
#pragma unroll
    for (int kb = 0; kb < 2; ++kb)
#pragma unroll
      for (int nb = 0; nb < 4; ++nb) {
        bf16x8 bk = *(const bf16x8*)&Ks[(nb * 16 + ln) * 64 + (((kb * 4 + lg) ^ x7) * 8)];
#pragma unroll
        for (int mb = 0; mb < 2; ++mb)
          s[mb][nb] = __builtin_amdgcn_mfma_f32_16x16x32_bf16(aq[mb][kb], bk, s[mb][nb], 0, 0, 0);
      }
    __builtin_amdgcn_s_setprio(0);

    // ---- softmax: exp2, packed bf16, P -> LDS (R10 swizzle, conflict-free) ----
    {
      unsigned int* PW = (unsigned int*)Pw;
#pragma unroll
      for (int mb = 0; mb < 2; ++mb)
#pragma unroll
        for (int r = 0; r < 4; ++r) {
          int q = mb * 16 + lg * 4 + r;
          float p0 = EXP2(s[mb][0][r]);
          float p1 = EXP2(s[mb][1][r]);
          float p2 = EXP2(s[mb][2][r]);
          float p3 = EXP2(s[mb][3][r]);
          unsigned int d0, d1;
          asm("v_cvt_pk_bf16_f32 %0, %1, %2" : "=v"(d0) : "v"(p0), "v"(p1));
          asm("v_cvt_pk_bf16_f32 %0, %1, %2" : "=v"(d1) : "v"(p2), "v"(p3));
          int dwb = q * 32;
          int x = (q & 7) << 2;
          PW[dwb + (ln ^ x)] = d0;            // keys (ln, ln+16)
          PW[dwb + ((16 + ln) ^ x)] = d1;     // keys (32+ln, 48+ln)
          l_p[mb][r] += (p0 + p1) + (p2 + p3);
        }
    }
    asm volatile("s_waitcnt lgkmcnt(0)" ::: "memory");
    __builtin_amdgcn_sched_barrier(0);

    // ---- O += P @ V, V-frags from swizzled LDS ----
    __builtin_amdgcn_s_setprio(1);
#pragma unroll
    for (int kb = 0; kb < 2; ++kb) {
      bf16x8 ap[2];
#pragma unroll
      for (int mb = 0; mb < 2; ++mb) {
        int row = mb * 16 + ln;
        ap[mb] = *(const bf16x8*)&Pw[row * 64 +
                                     (((kb * 16 + lg * 4) ^ ((row & 7) << 2)) << 1)];
      }
#pragma unroll
      for (int nd = 0; nd < 4; ++nd) {
        bf16x8 bv = *(const bf16x8*)&Vs[(nd * 16 + ln) * 64 + (((kb * 4 + lg) ^ x7) * 8)];
#pragma unroll
        for (int mb = 0; mb < 2; ++mb)
          acc_o[mb][nd] = __builtin_amdgcn_mfma_f32_16x16x32_bf16(ap[mb], bv, acc_o[mb][nd], 0, 0, 0);
      }
    }
    __builtin_amdgcn_s_setprio(0);
  }

  // epilogue: reduce l over the 16-lane key group, divide, store
#pragma unroll
  for (int mb = 0; mb < 2; ++mb)
#pragma unroll
    for (int r = 0; r < 4; ++r) {
      float ls = l_p[mb][r];
      ls += __shfl_xor(ls, 1);
      ls += __shfl_xor(ls, 2);
      ls += __shfl_xor(ls, 4);
      ls += __shfl_xor(ls, 8);
      float inv = 1.f / ls;
      int row = qrow0 + mb * 16 + lg * 4 + r;
#pragma unroll
      for (int nd = 0; nd < 4; ++nd)
        O[base + row * 64 + nd * 16 + ln] = f2bf(acc_o[mb][nd][r] * inv);
    }
}

// ---------------- launch ----------------
extern "C" void kernel_launch(void* const* d_in, const int* in_sizes, int n_in,
                              void* d_out, int out_size, void* d_ws, size_t ws_size,
                              hipStream_t stream) {
  const float* query = (const float*)d_in[0];
  const float* key   = (const float*)d_in[1];
  const float* value = (const float*)d_in[2];
  const float* Wq = (const float*)d_in[3];
  const float* bq = (const float*)d_in[4];
  const float* Wk = (const float*)d_in[5];
  const float* bk = (const float*)d_in[6];
  const float* Wv = (const float*)d_in[7];
  const float* bv = (const float*)d_in[8];
  const float* Wo = (const float*)d_in[9];
  const float* bo = (const float*)d_in[10];

  const int ACT = 4096 * 1024;
  const int WEL = 1024 * 1024;
  const int M = 4096, N = 1024, Kd = 1024;
  const float ALPHA_Q = 0.125f * 1.44269504f;   // 1/sqrt(64) * log2(e)

  char* ws = (char*)d_ws;
  dim3 blk(256);

  if (ws_size >= (size_t)(56u * 1024u * 1024u)) {
    // ---- Path A: merged converts + batched QKV + staged attention ----
    unsigned short* Xq  = (unsigned short*)(ws);
    unsigned short* Vtb = (unsigned short*)(ws);
    unsigned short* Xk  = (unsigned short*)(ws + (8u << 20));
    unsigned short* Ob  = (unsigned short*)(ws + (8u << 20));
    unsigned short* Xv  = (unsigned short*)(ws + (16u << 20));
    unsigned short* Wqb = (unsigned short*)(ws + (24u << 20));
    unsigned short* Wkb = (unsigned short*)(ws + (26u << 20));
    unsigned short* Wvb = (unsigned short*)(ws + (28u << 20));
    unsigned short* Wob = (unsigned short*)(ws + (30u << 20));
    unsigned short* Qb  = (unsigned short*)(ws + (32u << 20));
    unsigned short* Kb  = (unsigned short*)(ws + (40u << 20));
    unsigned short* Vb  = (unsigned short*)(ws + (48u << 20));

    cvt_all<<<dim3(8192), blk, 0, stream>>>(query, key, value, Wq, Wk, Wv, Wo,
                                            Xq, Xk, Xv, Wqb, Wkb, Wvb, Wob);
    gemm_qkv<<<dim3(768), blk, 0, stream>>>(Xq, Xk, Xv, Wqb, Wkb, Wvb,
                                            bq, bk, bv, Qb, Kb, Vb, ALPHA_Q);
    transpose_v<<<dim3(1024), blk, 0, stream>>>(Vb, Vtb);
    attn_kernel<<<dim3(512), blk, 0, stream>>>(Qb, Kb, Vtb, Ob);
    gemm_bt64_f32<<<dim3(512), blk, 0, stream>>>(Ob, Wob, bo, (float*)d_out);
  } else {
    // ---- Path B: sequential (34 MB workspace) ----
    unsigned short* X   = (unsigned short*)(ws);
    unsigned short* Vtb = (unsigned short*)(ws);
    unsigned short* W   = (unsigned short*)(ws + 8388608);
    unsigned short* Qb  = (unsigned short*)(ws + 10485760);
    unsigned short* Kb  = (unsigned short*)(ws + 18874368);
    unsigned short* Vb  = (unsigned short*)(ws + 27262976);
    unsigned short* Ob  = (unsigned short*)(ws + 27262976);

    cvt_f32_bf16<<<dim3(ACT / 2048), blk, 0, stream>>>(query, X, ACT);
    cvt_f32_bf16<<<dim3(WEL / 2048), blk, 0, stream>>>(Wq, W, WEL);
    gemm_bt<0><<<dim3(256), blk, 0, stream>>>(X, W, bq, (void*)Qb, M, N, Kd, ALPHA_Q);

    cvt_f32_bf16<<<dim3(ACT / 2048), blk, 0, stream>>>(key, X, ACT);
    cvt_f32_bf16<<<dim3(WEL / 2048), blk, 0, stream>>>(Wk, W, WEL);
    gemm_bt<0><<<dim3(256), blk, 0, stream>>>(X, W, bk, (void*)Kb, M, N, Kd, 1.0f);

    cvt_f32_bf16<<<dim3(ACT / 2048), blk, 0, stream>>>(value, X, ACT);
    cvt_f32_bf16<<<dim3(WEL / 2048), blk, 0, stream>>>(Wv, W, WEL);
    gemm_bt<0><<<dim3(256), blk, 0, stream>>>(X, W, bv, (void*)Vb, M, N, Kd, 1.0f);

    transpose_v<<<dim3(1024), blk, 0, stream>>>(Vb, Vtb);
    cvt_f32_bf16<<<dim3(WEL / 2048), blk, 0, stream>>>(Wo, W, WEL);
    attn_kernel<<<dim3(512), blk, 0, stream>>>(Qb, Kb, Vtb, Ob);
    gemm_bt64_f32<<<dim3(512), blk, 0, stream>>>(Ob, W, bo, (float*)d_out);
  }
}